// Round 1
// baseline (2534.208 us; speedup 1.0000x reference)
//
#include <hip/hip_runtime.h>

#define B_  32
#define N_  512
#define D_  791
#define H_  7
#define DK_ 113
#define M_  (B_*N_)

// ---------------- GEMM: C = A(M x D) @ W(D x D) + bias ----------------
#define BM 64
#define BN 64
#define BK 16

__global__ __launch_bounds__(256)
void gemm_bias_kernel(const float* __restrict__ A, const float* __restrict__ W,
                      const float* __restrict__ bias, float* __restrict__ C)
{
    __shared__ float As[BK][BM];
    __shared__ float Bs[BK][BN];
    const int bx = blockIdx.x;      // col tile
    const int by = blockIdx.y;      // row tile
    const int t  = threadIdx.x;
    const int tx = t & 15, ty = t >> 4;
    const int row0 = by * BM, col0 = bx * BN;

    float acc[4][4] = {};

    const int lr = t >> 2;          // 0..63  A row within tile
    const int lk = (t & 3) * 4;     // 0,4,8,12
    const int wr = t >> 4;          // 0..15  W k-row within tile
    const int wc = (t & 15) * 4;    // 0..60

    for (int k0 = 0; k0 < D_; k0 += BK) {
        {   // A tile -> As[k][m]
            const int gr = row0 + lr;
            #pragma unroll
            for (int i = 0; i < 4; ++i) {
                int gk = k0 + lk + i;
                As[lk + i][lr] = (gk < D_) ? A[(size_t)gr * D_ + gk] : 0.f;
            }
        }
        {   // W tile -> Bs[k][n]
            const int gk = k0 + wr;
            #pragma unroll
            for (int i = 0; i < 4; ++i) {
                int gc = col0 + wc + i;
                Bs[wr][wc + i] = (gk < D_ && gc < D_) ? W[(size_t)gk * D_ + gc] : 0.f;
            }
        }
        __syncthreads();
        #pragma unroll
        for (int k = 0; k < BK; ++k) {
            float a[4], b[4];
            #pragma unroll
            for (int i = 0; i < 4; ++i) a[i] = As[k][ty*4+i];
            #pragma unroll
            for (int j = 0; j < 4; ++j) b[j] = Bs[k][tx*4+j];
            #pragma unroll
            for (int i = 0; i < 4; ++i)
                #pragma unroll
                for (int j = 0; j < 4; ++j)
                    acc[i][j] += a[i] * b[j];
        }
        __syncthreads();
    }

    #pragma unroll
    for (int i = 0; i < 4; ++i) {
        int gr = row0 + ty*4 + i;
        #pragma unroll
        for (int j = 0; j < 4; ++j) {
            int gc = col0 + tx*4 + j;
            if (gc < D_) {
                float v = acc[i][j];
                if (bias) v += bias[gc];
                C[(size_t)gr * D_ + gc] = v;
            }
        }
    }
}

// -------- attention: attn[b,n,m] = sum_h softmax_h(q.k/sqrt(dk))[n,m] --------
// One block owns TM=32 full rows (all 512 cols) -> softmax needs no cross-block
// reduction. Per-head scores recomputed in registers, heads accumulated.
#define TM 32

__global__ __launch_bounds__(256)
void attn_kernel(const float* __restrict__ Q, const float* __restrict__ K,
                 float* __restrict__ attn)
{
    __shared__ float Ks[N_][8];   // 16 KB
    __shared__ float Qs[TM][8];   // 1 KB
    const int b  = blockIdx.y;
    const int r0 = blockIdx.x * TM;
    const int t  = threadIdx.x;
    const int rl = t >> 3;          // 0..31 local row
    const int cg = t & 7;           // col group

    const float scale = 0.094072086f; // 1/sqrt(113)
    float accA[64];
    #pragma unroll
    for (int j = 0; j < 64; ++j) accA[j] = 0.f;

    const float* Qb = Q + ((size_t)b * N_ + r0) * D_;
    const float* Kb = K + (size_t)b * N_ * D_;

    for (int h = 0; h < H_; ++h) {
        const int dbase = h * DK_;
        float s[64];
        #pragma unroll
        for (int j = 0; j < 64; ++j) s[j] = 0.f;

        for (int dc = 0; dc < DK_; dc += 8) {
            for (int i = 0; i < 16; ++i) {           // K chunk: 512 x 8
                int idx = t + 256 * i;
                int c = idx >> 3, d = idx & 7;
                float v = 0.f;
                if (dc + d < DK_) v = Kb[(size_t)c * D_ + dbase + dc + d];
                Ks[c][d] = v;
            }
            {                                         // Q chunk: 32 x 8
                int rr = t >> 3, d = t & 7;
                float v = 0.f;
                if (dc + d < DK_) v = Qb[(size_t)rr * D_ + dbase + dc + d];
                Qs[rr][d] = v;
            }
            __syncthreads();
            const float4 q0 = *(const float4*)&Qs[rl][0];
            const float4 q1 = *(const float4*)&Qs[rl][4];
            #pragma unroll
            for (int j = 0; j < 64; ++j) {
                const float4 k0 = *(const float4*)&Ks[cg + 8*j][0];
                const float4 k1 = *(const float4*)&Ks[cg + 8*j][4];
                s[j] += q0.x*k0.x + q0.y*k0.y + q0.z*k0.z + q0.w*k0.w
                      + q1.x*k1.x + q1.y*k1.y + q1.z*k1.z + q1.w*k1.w;
            }
            __syncthreads();
        }
        // row softmax: 8 lanes per row, contiguous within a wave
        float mymax = -1e30f;
        #pragma unroll
        for (int j = 0; j < 64; ++j) { s[j] *= scale; mymax = fmaxf(mymax, s[j]); }
        #pragma unroll
        for (int m = 1; m < 8; m <<= 1) mymax = fmaxf(mymax, __shfl_xor(mymax, m));
        float mysum = 0.f;
        #pragma unroll
        for (int j = 0; j < 64; ++j) { s[j] = __expf(s[j] - mymax); mysum += s[j]; }
        #pragma unroll
        for (int m = 1; m < 8; m <<= 1) mysum += __shfl_xor(mysum, m);
        const float rinv = 1.f / mysum;
        #pragma unroll
        for (int j = 0; j < 64; ++j) accA[j] += s[j] * rinv;
    }
    float* arow = attn + ((size_t)b * N_ + (r0 + rl)) * N_;
    #pragma unroll
    for (int j = 0; j < 64; ++j) arow[cg + 8*j] = accA[j];
}

// -------- per-batch top-2 + diagonal extraction (attn lives in d_out) --------
__global__ __launch_bounds__(256)
void topdiag_kernel(const float* __restrict__ attn, float* __restrict__ diag,
                    int* __restrict__ tidx, float* __restrict__ tval)
{
    const int b = blockIdx.x;
    const int t = threadIdx.x;
    const float* ab = attn + (size_t)b * N_ * N_;
    for (int n = t; n < N_; n += 256) diag[b * N_ + n] = ab[(size_t)n * N_ + n];

    float v1 = -1e30f, v2 = -1e30f; int i1 = 0, i2 = 0;
    for (int i = t; i < N_*N_; i += 256) {
        float v = ab[i];
        if (v > v1)      { v2 = v1; i2 = i1; v1 = v; i1 = i; }
        else if (v > v2) { v2 = v;  i2 = i; }
    }
    __shared__ float sv1[256], sv2[256];
    __shared__ int   si1[256], si2[256];
    sv1[t] = v1; sv2[t] = v2; si1[t] = i1; si2[t] = i2;
    __syncthreads();
    if (t == 0) {
        float g1 = -1e30f, g2 = -1e30f; int gi1 = 0, gi2 = 0;
        for (int k = 0; k < 256; ++k) {
            float a = sv1[k]; int ia = si1[k];
            if (a > g1)      { g2 = g1; gi2 = gi1; g1 = a; gi1 = ia; }
            else if (a > g2) { g2 = a; gi2 = ia; }
            a = sv2[k]; ia = si2[k];
            if (a > g1)      { g2 = g1; gi2 = gi1; g1 = a; gi1 = ia; }
            else if (a > g2) { g2 = a; gi2 = ia; }
        }
        int r1 = gi1 / N_, c1 = gi1 % N_;
        int r2 = gi2 / N_, c2 = gi2 % N_;
        tidx[b*4+0] = r1; tidx[b*4+1] = c1; tidx[b*4+2] = r2; tidx[b*4+3] = c2;
        tval[b*4+0] = ab[(size_t)r1*N_ + c1];
        tval[b*4+1] = ab[(size_t)c1*N_ + r1];
        tval[b*4+2] = ab[(size_t)r2*N_ + c2];
        tval[b*4+3] = ab[(size_t)c2*N_ + r2];
    }
}

// -------- sparse graph-conv epilogue: out = relu((att_adj@Hd)/denom + b) -----
__global__ __launch_bounds__(256)
void out_kernel(const float* __restrict__ Hd, const float* __restrict__ diag,
                const int* __restrict__ tidx, const float* __restrict__ tval,
                const float* __restrict__ bgc, float* __restrict__ out)
{
    const int bn = blockIdx.x;         // 0..16383
    const int b = bn >> 9, n = bn & 511;
    const int t = threadIdx.x;

    const int r1 = tidx[b*4+0], c1 = tidx[b*4+1];
    const int r2 = tidx[b*4+2], c2 = tidx[b*4+3];

    int   mc[4]; float mv[4]; int nc = 0;
    if (r1 != c1) {
        if (n == r1) { mc[nc] = c1; mv[nc] = tval[b*4+0]; ++nc; }
        if (n == c1) { mc[nc] = r1; mv[nc] = tval[b*4+1]; ++nc; }
    }
    if (r2 != c2) {
        if (n == r2) { mc[nc] = c2; mv[nc] = tval[b*4+2]; ++nc; }
        if (n == c2) { mc[nc] = r2; mv[nc] = tval[b*4+3]; ++nc; }
    }
    const float dg = diag[bn];
    float denom = dg + 1.0f;
    for (int i = 0; i < nc; ++i) denom += mv[i];
    const float rd = 1.f / denom;

    const float* hn = Hd + (size_t)bn * D_;
    for (int d = t; d < D_; d += 256) {
        float acc = dg * hn[d];
        for (int i = 0; i < nc; ++i)
            acc += mv[i] * Hd[(size_t)(b * N_ + mc[i]) * D_ + d];
        float o = acc * rd + bgc[d];
        out[(size_t)bn * D_ + d] = fmaxf(o, 0.f);
    }
}

extern "C" void kernel_launch(void* const* d_in, const int* in_sizes, int n_in,
                              void* d_out, int out_size, void* d_ws, size_t ws_size,
                              hipStream_t stream)
{
    const float* X   = (const float*)d_in[0];
    const float* Wq  = (const float*)d_in[1];
    const float* bq  = (const float*)d_in[2];
    const float* Wk  = (const float*)d_in[3];
    const float* bk  = (const float*)d_in[4];
    const float* Wgc = (const float*)d_in[5];
    const float* bgc = (const float*)d_in[6];
    float* out = (float*)d_out;
    float* ws  = (float*)d_ws;

    float* Q    = ws;
    float* K    = ws + (size_t)M_ * D_;
    float* Hd   = ws + 2 * (size_t)M_ * D_;
    float* diag = ws + 3 * (size_t)M_ * D_;
    int*   tidx = (int*)(diag + M_);
    float* tval = (float*)(tidx + B_ * 4);
    float* attn = out;   // reuse d_out: 8.39M floats needed <= 12.96M available

    dim3 gg((D_ + BN - 1) / BN, M_ / BM);   // 13 x 256
    hipLaunchKernelGGL(gemm_bias_kernel, gg, dim3(256), 0, stream, X, Wq,  bq,  Q);
    hipLaunchKernelGGL(gemm_bias_kernel, gg, dim3(256), 0, stream, X, Wk,  bk,  K);
    hipLaunchKernelGGL(gemm_bias_kernel, gg, dim3(256), 0, stream, X, Wgc, (const float*)nullptr, Hd);
    hipLaunchKernelGGL(attn_kernel, dim3(N_ / TM, B_), dim3(256), 0, stream, Q, K, attn);
    hipLaunchKernelGGL(topdiag_kernel, dim3(B_), dim3(256), 0, stream, attn, diag, tidx, tval);
    hipLaunchKernelGGL(out_kernel, dim3(M_), dim3(256), 0, stream, Hd, diag, tidx, tval, bgc, out);
}

// Round 2
// 1957.501 us; speedup vs baseline: 1.2946x; 1.2946x over previous
//
#include <hip/hip_runtime.h>

#define B_  32
#define N_  512
#define D_  791
#define H_  7
#define DK_ 113
#define M_  (B_*N_)
#define KP_ 800              // D padded to multiple of 32 for MFMA K
#define NPAD_ 896            // D padded to multiple of 128 for N tiles

typedef __attribute__((ext_vector_type(8))) short bf16x8;
typedef __attribute__((ext_vector_type(4))) float f32x4;

// ---------------- bf16 split helpers (self-contained, RNE) ----------------
__device__ __forceinline__ ushort f2bf_rn(float x) {
    uint u = __float_as_uint(x);
    uint r = (u + 0x7FFFu + ((u >> 16) & 1u)) >> 16;
    return (ushort)r;
}
__device__ __forceinline__ float bf2f(ushort h) {
    return __uint_as_float(((uint)h) << 16);
}
__device__ __forceinline__ void split_bf16(float x, ushort& h, ushort& l) {
    h = f2bf_rn(x);
    l = f2bf_rn(x - bf2f(h));
}

// ---------- W -> transposed, padded, split: Bt[n][k], n<896, k<800 ----------
__global__ __launch_bounds__(256)
void castWt_kernel(const float* __restrict__ W0, const float* __restrict__ W1,
                   const float* __restrict__ W2,
                   ushort* __restrict__ B0h, ushort* __restrict__ B0l,
                   ushort* __restrict__ B1h, ushort* __restrict__ B1l,
                   ushort* __restrict__ B2h, ushort* __restrict__ B2l)
{
    const int n = blockIdx.x;                 // 0..895 (output row = W column)
    const int w = blockIdx.y;                 // which weight
    const float* W = (w == 0) ? W0 : (w == 1) ? W1 : W2;
    ushort* Bh = (w == 0) ? B0h : (w == 1) ? B1h : B2h;
    ushort* Bl = (w == 0) ? B0l : (w == 1) ? B1l : B2l;
    for (int k = threadIdx.x; k < KP_; k += 256) {
        float v = (n < D_ && k < D_) ? W[(size_t)k * D_ + n] : 0.f;
        ushort h, l; split_bf16(v, h, l);
        Bh[(size_t)n * KP_ + k] = h;
        Bl[(size_t)n * KP_ + k] = l;
    }
}

// ------- MFMA GEMM: C(M x 791) = X(M x 791) @ W + bias, split-bf16 ---------
// 128x128 tile, 4 waves, each wave 64x64 = 4x4 frags of 16x16x32.
// A (X) is split hi/lo on the fly during staging; B comes pre-split [n][k].
__global__ __launch_bounds__(256)
void gemm_mfma_kernel(const float* __restrict__ X,
                      const ushort* __restrict__ Bth, const ushort* __restrict__ Btl,
                      const float* __restrict__ bias, float* __restrict__ C)
{
    __shared__ ushort AsH[128*32], AsL[128*32];   // [row][k] stride 32
    __shared__ ushort BsH[128*32], BsL[128*32];   // [col][k] stride 32
    const int t    = threadIdx.x;
    const int lane = t & 63, wid = t >> 6;
    const int wr   = wid >> 1, wc = wid & 1;      // wave tile origin /64
    const int row0 = blockIdx.y * 128, col0 = blockIdx.x * 128;
    const int fr   = lane & 15, kg = (lane >> 4) * 8;

    f32x4 acc[4][4];
    #pragma unroll
    for (int m = 0; m < 4; ++m)
        #pragma unroll
        for (int n = 0; n < 4; ++n)
            acc[m][n] = (f32x4){0.f, 0.f, 0.f, 0.f};

    for (int k0 = 0; k0 < KP_; k0 += 32) {
        // ---- stage A: load fp32 X tile, split to hi/lo bf16 pairs ----
        #pragma unroll
        for (int i = 0; i < 8; ++i) {
            int idx = t + 256 * i;                 // 0..2047 (pairs)
            int r = idx >> 4, k2 = (idx & 15) * 2;
            int gk = k0 + k2;
            const float* xp = X + (size_t)(row0 + r) * D_ + gk;
            float x0 = (gk     < D_) ? xp[0] : 0.f;
            float x1 = (gk + 1 < D_) ? xp[1] : 0.f;
            ushort h0, l0, h1, l1;
            split_bf16(x0, h0, l0); split_bf16(x1, h1, l1);
            ((uint*)AsH)[idx] = (uint)h0 | ((uint)h1 << 16);
            ((uint*)AsL)[idx] = (uint)l0 | ((uint)l1 << 16);
        }
        // ---- stage B from pre-split Bt[n][k] ----
        #pragma unroll
        for (int i = 0; i < 2; ++i) {
            int idx = t + 256 * i;                 // 0..511 (8-elem chunks)
            int r = idx >> 2, kq = (idx & 3) * 8;
            size_t g = (size_t)(col0 + r) * KP_ + k0 + kq;
            *(bf16x8*)&BsH[idx * 8] = *(const bf16x8*)&Bth[g];
            *(bf16x8*)&BsL[idx * 8] = *(const bf16x8*)&Btl[g];
        }
        __syncthreads();

        bf16x8 aH[4], aL[4], bH[4], bL[4];
        #pragma unroll
        for (int m = 0; m < 4; ++m) {
            int r = wr * 64 + m * 16 + fr;
            aH[m] = *(const bf16x8*)&AsH[r * 32 + kg];
            aL[m] = *(const bf16x8*)&AsL[r * 32 + kg];
        }
        #pragma unroll
        for (int n = 0; n < 4; ++n) {
            int c = wc * 64 + n * 16 + fr;
            bH[n] = *(const bf16x8*)&BsH[c * 32 + kg];
            bL[n] = *(const bf16x8*)&BsL[c * 32 + kg];
        }
        #pragma unroll
        for (int m = 0; m < 4; ++m)
            #pragma unroll
            for (int n = 0; n < 4; ++n) {
                acc[m][n] = __builtin_amdgcn_mfma_f32_16x16x32_bf16(aH[m], bH[n], acc[m][n], 0, 0, 0);
                acc[m][n] = __builtin_amdgcn_mfma_f32_16x16x32_bf16(aH[m], bL[n], acc[m][n], 0, 0, 0);
                acc[m][n] = __builtin_amdgcn_mfma_f32_16x16x32_bf16(aL[m], bH[n], acc[m][n], 0, 0, 0);
            }
        __syncthreads();
    }

    // epilogue: D frag layout col=lane&15, row=(lane>>4)*4+j  [m89-verified]
    const int orow = (lane >> 4) * 4;
    #pragma unroll
    for (int n = 0; n < 4; ++n) {
        int gc = col0 + wc * 64 + n * 16 + fr;
        if (gc < D_) {
            float bb = bias ? bias[gc] : 0.f;
            #pragma unroll
            for (int m = 0; m < 4; ++m) {
                #pragma unroll
                for (int j = 0; j < 4; ++j) {
                    int gr = row0 + wr * 64 + m * 16 + orow + j;
                    C[(size_t)gr * D_ + gc] = acc[m][n][j] + bb;
                }
            }
        }
    }
}

// -------- attention: attn[b,n,m] = sum_h softmax_h(q.k/sqrt(dk))[n,m] --------
// Block: 32 rows x 512 cols, 256 threads. Thread (rg,cg): rows rg*8..+7,
// cols cg+64j. Per-k outer product: 64 B LDS per 128 FLOP.
#define CH 16
__global__ __launch_bounds__(256)
void attn_kernel2(const float* __restrict__ Q, const float* __restrict__ K,
                  float* __restrict__ attn)
{
    __shared__ float Ks[CH][516];   // [d][col], pad keeps banks spread
    __shared__ float Qs[CH][36];    // [d][row]
    const int b  = blockIdx.y;
    const int r0 = blockIdx.x * 32;
    const int t  = threadIdx.x;
    const int rg = t >> 6, cg = t & 63;
    const float scale = 0.09407208683f;  // 1/sqrt(113)

    float accA[8][8];
    #pragma unroll
    for (int i = 0; i < 8; ++i)
        #pragma unroll
        for (int j = 0; j < 8; ++j) accA[i][j] = 0.f;

    const float* Qb = Q + ((size_t)b * N_ + r0) * D_;
    const float* Kb = K + (size_t)b * N_ * D_;

    for (int h = 0; h < H_; ++h) {
        const int dbase = h * DK_;
        float s[8][8];
        #pragma unroll
        for (int i = 0; i < 8; ++i)
            #pragma unroll
            for (int j = 0; j < 8; ++j) s[i][j] = 0.f;

        for (int dc = 0; dc < 112; dc += CH) {
            {   // stage K chunk: 512 cols x 16 dims (coalesced along d)
                const int d = t & 15;
                int col = t >> 4;
                const float* kp = Kb + (size_t)col * D_ + dbase + dc + d;
                #pragma unroll
                for (int i = 0; i < 32; ++i) {
                    Ks[d][col] = *kp;
                    col += 16; kp += (size_t)16 * D_;
                }
            }
            {   // stage Q chunk: 32 rows x 16 dims
                const int d = t & 15;
                int row = t >> 4;
                const float* qp = Qb + (size_t)row * D_ + dbase + dc + d;
                #pragma unroll
                for (int i = 0; i < 2; ++i) {
                    Qs[d][row] = *qp;
                    row += 16; qp += (size_t)16 * D_;
                }
            }
            __syncthreads();
            #pragma unroll
            for (int k = 0; k < CH; ++k) {
                float a[8], bb[8];
                *(float4*)&a[0] = *(const float4*)&Qs[k][rg * 8];
                *(float4*)&a[4] = *(const float4*)&Qs[k][rg * 8 + 4];
                #pragma unroll
                for (int j = 0; j < 8; ++j) bb[j] = Ks[k][cg + 64 * j];
                #pragma unroll
                for (int i = 0; i < 8; ++i)
                    #pragma unroll
                    for (int j = 0; j < 8; ++j)
                        s[i][j] = fmaf(a[i], bb[j], s[i][j]);
            }
            __syncthreads();
        }
        {   // tail dim d = 112
            {
                int col = t;
                #pragma unroll
                for (int i = 0; i < 2; ++i) {
                    Ks[0][col] = Kb[(size_t)col * D_ + dbase + 112];
                    col += 256;
                }
                if (t < 32) Qs[0][t] = Qb[(size_t)t * D_ + dbase + 112];
            }
            __syncthreads();
            {
                float a[8], bb[8];
                *(float4*)&a[0] = *(const float4*)&Qs[0][rg * 8];
                *(float4*)&a[4] = *(const float4*)&Qs[0][rg * 8 + 4];
                #pragma unroll
                for (int j = 0; j < 8; ++j) bb[j] = Ks[0][cg + 64 * j];
                #pragma unroll
                for (int i = 0; i < 8; ++i)
                    #pragma unroll
                    for (int j = 0; j < 8; ++j)
                        s[i][j] = fmaf(a[i], bb[j], s[i][j]);
            }
            __syncthreads();
        }
        // row softmax: row rg*8+i owned by the 64 lanes of wave rg
        #pragma unroll
        for (int i = 0; i < 8; ++i) {
            float mx = -1e30f;
            #pragma unroll
            for (int j = 0; j < 8; ++j) { s[i][j] *= scale; mx = fmaxf(mx, s[i][j]); }
            #pragma unroll
            for (int msk = 1; msk < 64; msk <<= 1) mx = fmaxf(mx, __shfl_xor(mx, msk));
            float sum = 0.f;
            #pragma unroll
            for (int j = 0; j < 8; ++j) { float e = __expf(s[i][j] - mx); s[i][j] = e; sum += e; }
            #pragma unroll
            for (int msk = 1; msk < 64; msk <<= 1) sum += __shfl_xor(sum, msk);
            const float rinv = 1.f / sum;
            #pragma unroll
            for (int j = 0; j < 8; ++j) accA[i][j] += s[i][j] * rinv;
        }
    }
    #pragma unroll
    for (int i = 0; i < 8; ++i) {
        float* arow = attn + ((size_t)b * N_ + r0 + rg * 8 + i) * N_;
        #pragma unroll
        for (int j = 0; j < 8; ++j) arow[cg + 64 * j] = accA[i][j];
    }
}

// -------- per-batch top-2 + diagonal extraction (attn lives in d_out) --------
__global__ __launch_bounds__(256)
void topdiag_kernel(const float* __restrict__ attn, float* __restrict__ diag,
                    int* __restrict__ tidx, float* __restrict__ tval)
{
    const int b = blockIdx.x;
    const int t = threadIdx.x;
    const float* ab = attn + (size_t)b * N_ * N_;
    for (int n = t; n < N_; n += 256) diag[b * N_ + n] = ab[(size_t)n * N_ + n];

    float v1 = -1e30f, v2 = -1e30f; int i1 = 0, i2 = 0;
    for (int i = t; i < N_*N_; i += 256) {
        float v = ab[i];
        if (v > v1)      { v2 = v1; i2 = i1; v1 = v; i1 = i; }
        else if (v > v2) { v2 = v;  i2 = i; }
    }
    __shared__ float sv1[256], sv2[256];
    __shared__ int   si1[256], si2[256];
    sv1[t] = v1; sv2[t] = v2; si1[t] = i1; si2[t] = i2;
    __syncthreads();
    if (t == 0) {
        float g1 = -1e30f, g2 = -1e30f; int gi1 = 0, gi2 = 0;
        for (int k = 0; k < 256; ++k) {
            float a = sv1[k]; int ia = si1[k];
            if (a > g1)      { g2 = g1; gi2 = gi1; g1 = a; gi1 = ia; }
            else if (a > g2) { g2 = a; gi2 = ia; }
            a = sv2[k]; ia = si2[k];
            if (a > g1)      { g2 = g1; gi2 = gi1; g1 = a; gi1 = ia; }
            else if (a > g2) { g2 = a; gi2 = ia; }
        }
        int r1 = gi1 / N_, c1 = gi1 % N_;
        int r2 = gi2 / N_, c2 = gi2 % N_;
        tidx[b*4+0] = r1; tidx[b*4+1] = c1; tidx[b*4+2] = r2; tidx[b*4+3] = c2;
        tval[b*4+0] = ab[(size_t)r1*N_ + c1];
        tval[b*4+1] = ab[(size_t)c1*N_ + r1];
        tval[b*4+2] = ab[(size_t)r2*N_ + c2];
        tval[b*4+3] = ab[(size_t)c2*N_ + r2];
    }
}

// -------- sparse graph-conv epilogue: out = relu((att_adj@Hd)/denom + b) -----
__global__ __launch_bounds__(256)
void out_kernel(const float* __restrict__ Hd, const float* __restrict__ diag,
                const int* __restrict__ tidx, const float* __restrict__ tval,
                const float* __restrict__ bgc, float* __restrict__ out)
{
    const int bn = blockIdx.x;         // 0..16383
    const int b = bn >> 9, n = bn & 511;
    const int t = threadIdx.x;

    const int r1 = tidx[b*4+0], c1 = tidx[b*4+1];
    const int r2 = tidx[b*4+2], c2 = tidx[b*4+3];

    int   mc[4]; float mv[4]; int nc = 0;
    if (r1 != c1) {
        if (n == r1) { mc[nc] = c1; mv[nc] = tval[b*4+0]; ++nc; }
        if (n == c1) { mc[nc] = r1; mv[nc] = tval[b*4+1]; ++nc; }
    }
    if (r2 != c2) {
        if (n == r2) { mc[nc] = c2; mv[nc] = tval[b*4+2]; ++nc; }
        if (n == c2) { mc[nc] = r2; mv[nc] = tval[b*4+3]; ++nc; }
    }
    const float dg = diag[bn];
    float denom = dg + 1.0f;
    for (int i = 0; i < nc; ++i) denom += mv[i];
    const float rd = 1.f / denom;

    const float* hn = Hd + (size_t)bn * D_;
    for (int d = t; d < D_; d += 256) {
        float acc = dg * hn[d];
        for (int i = 0; i < nc; ++i)
            acc += mv[i] * Hd[(size_t)(b * N_ + mc[i]) * D_ + d];
        float o = acc * rd + bgc[d];
        out[(size_t)bn * D_ + d] = fmaxf(o, 0.f);
    }
}

extern "C" void kernel_launch(void* const* d_in, const int* in_sizes, int n_in,
                              void* d_out, int out_size, void* d_ws, size_t ws_size,
                              hipStream_t stream)
{
    const float* X   = (const float*)d_in[0];
    const float* Wq  = (const float*)d_in[1];
    const float* bq  = (const float*)d_in[2];
    const float* Wk  = (const float*)d_in[3];
    const float* bk  = (const float*)d_in[4];
    const float* Wgc = (const float*)d_in[5];
    const float* bgc = (const float*)d_in[6];
    float* out = (float*)d_out;
    float* ws  = (float*)d_ws;

    const size_t MD = (size_t)M_ * D_;          // 12,959,744
    float* Q    = ws;
    float* Kf   = ws + MD;
    float* Hd   = ws + 2 * MD;
    float* diag = ws + 3 * MD;                  // 16384 floats
    int*   tidx = (int*)(diag + M_);            // 128 ints
    float* tval = (float*)(tidx + 128);         // 128 floats
    ushort* Bt  = (ushort*)(tval + 128);        // 16B-aligned by construction
    const size_t BSZ = (size_t)NPAD_ * KP_;     // 716,800 ushorts per part
    ushort* Bqh = Bt;            ushort* Bql = Bt + BSZ;
    ushort* Bkh = Bt + 2 * BSZ;  ushort* Bkl = Bt + 3 * BSZ;
    ushort* Bgh = Bt + 4 * BSZ;  ushort* Bgl = Bt + 5 * BSZ;
    float* attn = out;   // reuse d_out as attn scratch (8.39M <= 12.96M floats)

    hipLaunchKernelGGL(castWt_kernel, dim3(NPAD_, 3), dim3(256), 0, stream,
                       Wq, Wk, Wgc, Bqh, Bql, Bkh, Bkl, Bgh, Bgl);

    dim3 gg(7, 128);    // N tiles x M tiles
    hipLaunchKernelGGL(gemm_mfma_kernel, gg, dim3(256), 0, stream, X, Bqh, Bql, bq,  Q);
    hipLaunchKernelGGL(gemm_mfma_kernel, gg, dim3(256), 0, stream, X, Bkh, Bkl, bk,  Kf);
    hipLaunchKernelGGL(gemm_mfma_kernel, gg, dim3(256), 0, stream, X, Bgh, Bgl, (const float*)nullptr, Hd);

    hipLaunchKernelGGL(attn_kernel2, dim3(16, 32), dim3(256), 0, stream, Q, Kf, attn);
    hipLaunchKernelGGL(topdiag_kernel, dim3(B_), dim3(256), 0, stream, attn, diag, tidx, tval);
    hipLaunchKernelGGL(out_kernel, dim3(M_), dim3(256), 0, stream, Hd, diag, tidx, tval, bgc, out);
}

// Round 6
// 1109.868 us; speedup vs baseline: 2.2833x; 1.7637x over previous
//
#include <hip/hip_runtime.h>

#define B_  32
#define N_  512
#define D_  791
#define H_  7
#define DK_ 113
#define M_  (B_*N_)
#define KP_ 800              // GEMM K-dim (D padded to mult of 32)
#define DP_ 896              // per-head-padded col dim: 7 heads x 128
#define LP_ 40               // padded LDS row stride (ushorts) for GEMM tiles

typedef __attribute__((ext_vector_type(8))) short bf16x8;
typedef __attribute__((ext_vector_type(4))) float f32x4;

// ---------------- bf16 split helpers (RNE) ----------------
__device__ __forceinline__ ushort f2bf_rn(float x) {
    uint u = __float_as_uint(x);
    uint r = (u + 0x7FFFu + ((u >> 16) & 1u)) >> 16;
    return (ushort)r;
}
__device__ __forceinline__ float bf2f(ushort h) {
    return __uint_as_float(((uint)h) << 16);
}
__device__ __forceinline__ void split_bf16(float x, ushort& h, ushort& l) {
    h = f2bf_rn(x);
    l = f2bf_rn(x - bf2f(h));
}

// ---------- W -> transposed/padded/split Bt[pc][k] ----------
// w<2 (Wq,Wk): pc = h*128+off maps to source col h*113+off (off<113), else zeros
// w==2 (Wgc):  pc maps to source col pc (pc<791), else zeros
__global__ __launch_bounds__(256)
void castWt_kernel(const float* __restrict__ W0, const float* __restrict__ W1,
                   const float* __restrict__ W2,
                   ushort* __restrict__ B0h, ushort* __restrict__ B0l,
                   ushort* __restrict__ B1h, ushort* __restrict__ B1l,
                   ushort* __restrict__ B2h, ushort* __restrict__ B2l)
{
    const int pc = blockIdx.x;                // 0..895
    const int w  = blockIdx.y;                // which weight
    const float* W = (w == 0) ? W0 : (w == 1) ? W1 : W2;
    ushort* Bh = (w == 0) ? B0h : (w == 1) ? B1h : B2h;
    ushort* Bl = (w == 0) ? B0l : (w == 1) ? B1l : B2l;
    int src;
    if (w == 2) src = (pc < D_) ? pc : -1;
    else { int hh = pc >> 7, off = pc & 127; src = (off < DK_) ? hh * DK_ + off : -1; }
    for (int k = threadIdx.x; k < KP_; k += 256) {
        float v = (src >= 0 && k < D_) ? W[(size_t)k * D_ + src] : 0.f;
        ushort h, l; split_bf16(v, h, l);
        Bh[(size_t)pc * KP_ + k] = h;
        Bl[(size_t)pc * KP_ + k] = l;
    }
}

// ------- MFMA GEMM: 128x128 tile, 4 waves, split-bf16 3-term ---------
// mode 0: fp32 packed output Cf[row][791] (cols>=791 dropped)
// mode 1: split-bf16 padded output Ch/Cl[row][896]
__global__ __launch_bounds__(256)
void gemm_mfma_kernel(const float* __restrict__ X,
                      const ushort* __restrict__ Bth, const ushort* __restrict__ Btl,
                      const float* __restrict__ bias,
                      float* __restrict__ Cf, ushort* __restrict__ Ch,
                      ushort* __restrict__ Cl, int mode)
{
    __shared__ ushort AsH[128*LP_], AsL[128*LP_];
    __shared__ ushort BsH[128*LP_], BsL[128*LP_];
    const int t    = threadIdx.x;
    const int lane = t & 63, wid = t >> 6;
    const int wr   = wid >> 1, wc = wid & 1;
    const int row0 = blockIdx.y * 128, col0 = blockIdx.x * 128;
    const int fr   = lane & 15, kg = (lane >> 4) * 8;

    f32x4 acc[4][4];
    #pragma unroll
    for (int m = 0; m < 4; ++m)
        #pragma unroll
        for (int n = 0; n < 4; ++n)
            acc[m][n] = (f32x4){0.f, 0.f, 0.f, 0.f};

    for (int k0 = 0; k0 < KP_; k0 += 32) {
        // stage A: fp32 load + on-the-fly split
        #pragma unroll
        for (int i = 0; i < 8; ++i) {
            int idx = t + 256 * i;                 // pair index
            int r = idx >> 4, k2 = (idx & 15) * 2;
            int gk = k0 + k2;
            const float* xp = X + (size_t)(row0 + r) * D_ + gk;
            float x0 = (gk     < D_) ? xp[0] : 0.f;
            float x1 = (gk + 1 < D_) ? xp[1] : 0.f;
            ushort h0, l0, h1, l1;
            split_bf16(x0, h0, l0); split_bf16(x1, h1, l1);
            ((uint*)AsH)[r * (LP_/2) + (idx & 15)] = (uint)h0 | ((uint)h1 << 16);
            ((uint*)AsL)[r * (LP_/2) + (idx & 15)] = (uint)l0 | ((uint)l1 << 16);
        }
        // stage B (pre-split)
        #pragma unroll
        for (int i = 0; i < 2; ++i) {
            int idx = t + 256 * i;
            int r = idx >> 2, kq = (idx & 3) * 8;
            size_t g = (size_t)(col0 + r) * KP_ + k0 + kq;
            *(bf16x8*)&BsH[r * LP_ + kq] = *(const bf16x8*)&Bth[g];
            *(bf16x8*)&BsL[r * LP_ + kq] = *(const bf16x8*)&Btl[g];
        }
        __syncthreads();

        bf16x8 aH[4], aL[4], bH[4], bL[4];
        #pragma unroll
        for (int m = 0; m < 4; ++m) {
            int r = wr * 64 + m * 16 + fr;
            aH[m] = *(const bf16x8*)&AsH[r * LP_ + kg];
            aL[m] = *(const bf16x8*)&AsL[r * LP_ + kg];
        }
        #pragma unroll
        for (int n = 0; n < 4; ++n) {
            int c = wc * 64 + n * 16 + fr;
            bH[n] = *(const bf16x8*)&BsH[c * LP_ + kg];
            bL[n] = *(const bf16x8*)&BsL[c * LP_ + kg];
        }
        #pragma unroll
        for (int m = 0; m < 4; ++m)
            #pragma unroll
            for (int n = 0; n < 4; ++n) {
                acc[m][n] = __builtin_amdgcn_mfma_f32_16x16x32_bf16(aH[m], bH[n], acc[m][n], 0, 0, 0);
                acc[m][n] = __builtin_amdgcn_mfma_f32_16x16x32_bf16(aH[m], bL[n], acc[m][n], 0, 0, 0);
                acc[m][n] = __builtin_amdgcn_mfma_f32_16x16x32_bf16(aL[m], bH[n], acc[m][n], 0, 0, 0);
            }
        __syncthreads();
    }

    // epilogue: D frag layout col=lane&15, row=(lane>>4)*4+j
    const int orow = (lane >> 4) * 4;
    if (mode == 0) {
        #pragma unroll
        for (int n = 0; n < 4; ++n) {
            int gc = col0 + wc * 64 + n * 16 + fr;
            if (gc < D_) {
                float bb = bias ? bias[gc] : 0.f;
                #pragma unroll
                for (int m = 0; m < 4; ++m)
                    #pragma unroll
                    for (int j = 0; j < 4; ++j) {
                        int gr = row0 + wr * 64 + m * 16 + orow + j;
                        Cf[(size_t)gr * D_ + gc] = acc[m][n][j] + bb;
                    }
            }
        }
    } else {
        #pragma unroll
        for (int n = 0; n < 4; ++n) {
            int pc = col0 + wc * 64 + n * 16 + fr;      // < 896 always
            int hh = pc >> 7, off = pc & 127;
            float bb = (off < DK_ && bias) ? bias[hh * DK_ + off] : 0.f;
            #pragma unroll
            for (int m = 0; m < 4; ++m)
                #pragma unroll
                for (int j = 0; j < 4; ++j) {
                    int gr = row0 + wr * 64 + m * 16 + orow + j;
                    float v = acc[m][n][j] + bb;        // pad cols: 0+0
                    ushort h, l; split_bf16(v, h, l);
                    Ch[(size_t)gr * DP_ + pc] = h;
                    Cl[(size_t)gr * DP_ + pc] = l;
                }
        }
    }
}

// -------- MFMA attention + fused per-block top-2 candidates --------
// Block: (batch, 32 q-rows). 4 waves split 512 keys (128 each).
// S frag: q=(lane>>4)*4+j (+m*16), key=w*128+n*16+(lane&15).
__global__ __launch_bounds__(256, 2)
void attn_mfma(const ushort* __restrict__ Qh, const ushort* __restrict__ Ql,
               const ushort* __restrict__ Kh, const ushort* __restrict__ Kl,
               float* __restrict__ attn, float* __restrict__ candv,
               int* __restrict__ candi)
{
    __shared__ ushort KsH[512*32];   // 32 KB, XOR-swizzled
    __shared__ ushort KsL[512*32];   // 32 KB
    __shared__ float redA[4][32];
    __shared__ float redB[4][32];
    __shared__ float wv[8]; __shared__ int wi[8];

    const int t = threadIdx.x, lane = t & 63, w = t >> 6;
    const int bid = blockIdx.x;
    const int swz = (bid & 7) * 64 + (bid >> 3);   // XCD-contiguous batches
    const int b = swz >> 4, r0 = (swz & 15) * 32;
    const int fr = lane & 15, kg = (lane >> 4) * 8;
    const float scale = 0.09407208683f;            // 1/sqrt(113)

    f32x4 accA[2][8];
    #pragma unroll
    for (int m = 0; m < 2; ++m)
        #pragma unroll
        for (int n = 0; n < 8; ++n) accA[m][n] = (f32x4){0.f,0.f,0.f,0.f};

    for (int h = 0; h < H_; ++h) {
        f32x4 S[2][8];
        #pragma unroll
        for (int m = 0; m < 2; ++m)
            #pragma unroll
            for (int n = 0; n < 8; ++n) S[m][n] = (f32x4){0.f,0.f,0.f,0.f};

        #pragma unroll
        for (int kk = 0; kk < 4; ++kk) {
            bf16x8 qH[2], qL[2];
            #pragma unroll
            for (int m = 0; m < 2; ++m) {
                size_t qo = (size_t)(b * N_ + r0 + m * 16 + fr) * DP_ + h * 128 + kk * 32 + kg;
                qH[m] = *(const bf16x8*)&Qh[qo];
                qL[m] = *(const bf16x8*)&Ql[qo];
            }
            // stage K chunk [512 keys][32], swizzled: col granule ^= (key&3)*8
            #pragma unroll
            for (int i = 0; i < 8; ++i) {
                int g = t + 256 * i;
                int key = g >> 2, c8 = (g & 3) * 8;
                size_t go = (size_t)(b * N_ + key) * DP_ + h * 128 + kk * 32 + c8;
                int lo = key * 32 + (c8 ^ ((key & 3) * 8));
                *(bf16x8*)&KsH[lo] = *(const bf16x8*)&Kh[go];
                *(bf16x8*)&KsL[lo] = *(const bf16x8*)&Kl[go];
            }
            __syncthreads();
            #pragma unroll
            for (int n = 0; n < 8; ++n) {
                int key = w * 128 + n * 16 + fr;
                int lo = key * 32 + (kg ^ ((key & 3) * 8));
                bf16x8 bH = *(const bf16x8*)&KsH[lo];
                bf16x8 bL = *(const bf16x8*)&KsL[lo];
                #pragma unroll
                for (int m = 0; m < 2; ++m) {
                    S[m][n] = __builtin_amdgcn_mfma_f32_16x16x32_bf16(qH[m], bH, S[m][n], 0, 0, 0);
                    S[m][n] = __builtin_amdgcn_mfma_f32_16x16x32_bf16(qH[m], bL, S[m][n], 0, 0, 0);
                    S[m][n] = __builtin_amdgcn_mfma_f32_16x16x32_bf16(qL[m], bH, S[m][n], 0, 0, 0);
                }
            }
            __syncthreads();
        }

        // ---- softmax over keys for each of the 32 rows ----
        float fm[2][4];
        #pragma unroll
        for (int m = 0; m < 2; ++m)
            #pragma unroll
            for (int j = 0; j < 4; ++j) {
                float mx = -1e30f;
                #pragma unroll
                for (int n = 0; n < 8; ++n) {
                    S[m][n][j] *= scale;
                    mx = fmaxf(mx, S[m][n][j]);
                }
                #pragma unroll
                for (int d = 1; d < 16; d <<= 1) mx = fmaxf(mx, __shfl_xor(mx, d));
                fm[m][j] = mx;
            }
        if ((lane & 15) == 0) {
            #pragma unroll
            for (int m = 0; m < 2; ++m)
                #pragma unroll
                for (int j = 0; j < 4; ++j)
                    redA[w][m * 16 + (lane >> 4) * 4 + j] = fm[m][j];
        }
        __syncthreads();
        #pragma unroll
        for (int m = 0; m < 2; ++m)
            #pragma unroll
            for (int j = 0; j < 4; ++j) {
                int q = m * 16 + (lane >> 4) * 4 + j;
                float mx = redA[0][q];
                mx = fmaxf(mx, redA[1][q]);
                mx = fmaxf(mx, redA[2][q]);
                mx = fmaxf(mx, redA[3][q]);
                fm[m][j] = mx;
            }
        float sm[2][4];
        #pragma unroll
        for (int m = 0; m < 2; ++m)
            #pragma unroll
            for (int j = 0; j < 4; ++j) {
                float s = 0.f;
                #pragma unroll
                for (int n = 0; n < 8; ++n) {
                    float e = __expf(S[m][n][j] - fm[m][j]);
                    S[m][n][j] = e; s += e;
                }
                #pragma unroll
                for (int d = 1; d < 16; d <<= 1) s += __shfl_xor(s, d);
                sm[m][j] = s;
            }
        if ((lane & 15) == 0) {
            #pragma unroll
            for (int m = 0; m < 2; ++m)
                #pragma unroll
                for (int j = 0; j < 4; ++j)
                    redB[w][m * 16 + (lane >> 4) * 4 + j] = sm[m][j];
        }
        __syncthreads();
        #pragma unroll
        for (int m = 0; m < 2; ++m)
            #pragma unroll
            for (int j = 0; j < 4; ++j) {
                int q = m * 16 + (lane >> 4) * 4 + j;
                float s = redB[0][q] + redB[1][q] + redB[2][q] + redB[3][q];
                float rinv = 1.f / s;
                #pragma unroll
                for (int n = 0; n < 8; ++n)
                    accA[m][n][j] += S[m][n][j] * rinv;
            }
        __syncthreads();   // redA/redB safe for next head
    }

    // ---- write attn rows (coalesced 16-lane segments) ----
    float* ab = attn + (size_t)b * N_ * N_;
    #pragma unroll
    for (int m = 0; m < 2; ++m)
        #pragma unroll
        for (int j = 0; j < 4; ++j) {
            int row = r0 + m * 16 + (lane >> 4) * 4 + j;
            float* ar = ab + (size_t)row * N_;
            #pragma unroll
            for (int n = 0; n < 8; ++n)
                ar[w * 128 + n * 16 + fr] = accA[m][n][j];
        }

    // ---- block-local top-2 over register values ----
    float v1 = -1e30f, v2 = -1e30f; int i1 = 0, i2 = 0;
    #pragma unroll
    for (int m = 0; m < 2; ++m)
        #pragma unroll
        for (int n = 0; n < 8; ++n)
            #pragma unroll
            for (int j = 0; j < 4; ++j) {
                float v = accA[m][n][j];
                int row = r0 + m * 16 + (lane >> 4) * 4 + j;
                int col = w * 128 + n * 16 + fr;
                int idx = row * N_ + col;
                if (v > v1)      { v2 = v1; i2 = i1; v1 = v; i1 = idx; }
                else if (v > v2) { v2 = v;  i2 = idx; }
            }
    #pragma unroll
    for (int d = 1; d < 64; d <<= 1) {
        float ov1 = __shfl_xor(v1, d); int oi1 = __shfl_xor(i1, d);
        float ov2 = __shfl_xor(v2, d); int oi2 = __shfl_xor(i2, d);
        if (ov1 > v1)      { v2 = v1; i2 = i1; v1 = ov1; i1 = oi1; }
        else if (ov1 > v2) { v2 = ov1; i2 = oi1; }
        if (ov2 > v1)      { v2 = v1; i2 = i1; v1 = ov2; i1 = oi2; }
        else if (ov2 > v2) { v2 = ov2; i2 = oi2; }
    }
    if (lane == 0) { wv[w*2] = v1; wi[w*2] = i1; wv[w*2+1] = v2; wi[w*2+1] = i2; }
    __syncthreads();
    if (t == 0) {
        float g1 = -1e30f, g2 = -1e30f; int gi1 = 0, gi2 = 0;
        for (int e = 0; e < 8; ++e) {
            float v = wv[e]; int ii = wi[e];
            if (v > g1)      { g2 = g1; gi2 = gi1; g1 = v; gi1 = ii; }
            else if (v > g2) { g2 = v; gi2 = ii; }
        }
        int cb = (b * 16 + (swz & 15)) * 2;
        candv[cb] = g1; candi[cb] = gi1;
        candv[cb+1] = g2; candi[cb+1] = gi2;
    }
}

// -------- merge per-batch candidates + extract diag + gather transposes -----
__global__ __launch_bounds__(256)
void merge_kernel(const float* __restrict__ attn, const float* __restrict__ candv,
                  const int* __restrict__ candi, float* __restrict__ diag,
                  int* __restrict__ tidx, float* __restrict__ tval)
{
    const int b = blockIdx.x, t = threadIdx.x;
    const float* ab = attn + (size_t)b * N_ * N_;
    for (int n = t; n < N_; n += 256) diag[b * N_ + n] = ab[(size_t)n * N_ + n];
    if (t == 0) {
        float v1 = -1e30f, v2 = -1e30f; int i1 = 0, i2 = 0;
        for (int s = 0; s < 32; ++s) {
            float v = candv[b * 32 + s]; int ii = candi[b * 32 + s];
            if (v > v1)      { v2 = v1; i2 = i1; v1 = v; i1 = ii; }
            else if (v > v2) { v2 = v; i2 = ii; }
        }
        int r1 = i1 / N_, c1 = i1 % N_;
        int r2 = i2 / N_, c2 = i2 % N_;
        tidx[b*4+0] = r1; tidx[b*4+1] = c1; tidx[b*4+2] = r2; tidx[b*4+3] = c2;
        tval[b*4+0] = ab[(size_t)r1 * N_ + c1];
        tval[b*4+1] = ab[(size_t)c1 * N_ + r1];
        tval[b*4+2] = ab[(size_t)r2 * N_ + c2];
        tval[b*4+3] = ab[(size_t)c2 * N_ + r2];
    }
}

// -------- sparse graph-conv epilogue --------
__global__ __launch_bounds__(256)
void out_kernel(const float* __restrict__ Hd, const float* __restrict__ diag,
                const int* __restrict__ tidx, const float* __restrict__ tval,
                const float* __restrict__ bgc, float* __restrict__ out)
{
    const int bn = blockIdx.x;
    const int b = bn >> 9, n = bn & 511;
    const int t = threadIdx.x;

    const int r1 = tidx[b*4+0], c1 = tidx[b*4+1];
    const int r2 = tidx[b*4+2], c2 = tidx[b*4+3];

    int   mc[4]; float mv[4]; int nc = 0;
    if (r1 != c1) {
        if (n == r1) { mc[nc] = c1; mv[nc] = tval[b*4+0]; ++nc; }
        if (n == c1) { mc[nc] = r1; mv[nc] = tval[b*4+1]; ++nc; }
    }
    if (r2 != c2) {
        if (n == r2) { mc[nc] = c2; mv[nc] = tval[b*4+2]; ++nc; }
        if (n == c2) { mc[nc] = r2; mv[nc] = tval[b*4+3]; ++nc; }
    }
    const float dg = diag[bn];
    float denom = dg + 1.0f;
    for (int i = 0; i < nc; ++i) denom += mv[i];
    const float rd = 1.f / denom;

    const float* hn = Hd + (size_t)bn * D_;
    for (int d = t; d < D_; d += 256) {
        float acc = dg * hn[d];
        for (int i = 0; i < nc; ++i)
            acc += mv[i] * Hd[(size_t)(b * N_ + mc[i]) * D_ + d];
        float o = acc * rd + bgc[d];
        out[(size_t)bn * D_ + d] = fmaxf(o, 0.f);
    }
}

extern "C" void kernel_launch(void* const* d_in, const int* in_sizes, int n_in,
                              void* d_out, int out_size, void* d_ws, size_t ws_size,
                              hipStream_t stream)
{
    const float* X   = (const float*)d_in[0];
    const float* Wq  = (const float*)d_in[1];
    const float* bq  = (const float*)d_in[2];
    const float* Wk  = (const float*)d_in[3];
    const float* bk  = (const float*)d_in[4];
    const float* Wgc = (const float*)d_in[5];
    const float* bgc = (const float*)d_in[6];
    float* out = (float*)d_out;

    ushort* wsu = (ushort*)d_ws;
    const size_t MDP = (size_t)M_ * DP_;          // 14,680,064
    ushort* Qh = wsu;
    ushort* Ql = wsu + MDP;
    ushort* Kh = wsu + 2 * MDP;
    ushort* Kl = wsu + 3 * MDP;
    ushort* Bt = wsu + 4 * MDP;
    const size_t BSZ = (size_t)DP_ * KP_;         // 716,800
    ushort* Bqh = Bt;            ushort* Bql = Bt + BSZ;
    ushort* Bkh = Bt + 2 * BSZ;  ushort* Bkl = Bt + 3 * BSZ;
    ushort* Bgh = Bt + 4 * BSZ;  ushort* Bgl = Bt + 5 * BSZ;
    float* diag  = (float*)(Bt + 6 * BSZ);        // M_ floats
    int*   tidx  = (int*)(diag + M_);             // 128
    float* tval  = (float*)(tidx + 128);          // 128
    float* candv = tval + 128;                    // 1024
    int*   candi = (int*)(candv + 1024);          // 1024
    float* Hd    = (float*)d_ws;                  // aliases Qh/Ql AFTER attn done
    float* attn  = out;                           // d_out as attn scratch

    hipLaunchKernelGGL(castWt_kernel, dim3(DP_, 3), dim3(256), 0, stream,
                       Wq, Wk, Wgc, Bqh, Bql, Bkh, Bkl, Bgh, Bgl);

    dim3 gg(7, 128);    // 896 cols x 16384 rows
    hipLaunchKernelGGL(gemm_mfma_kernel, gg, dim3(256), 0, stream,
                       X, Bqh, Bql, bq, (float*)nullptr, Qh, Ql, 1);
    hipLaunchKernelGGL(gemm_mfma_kernel, gg, dim3(256), 0, stream,
                       X, Bkh, Bkl, bk, (float*)nullptr, Kh, Kl, 1);

    hipLaunchKernelGGL(attn_mfma, dim3(512), dim3(256), 0, stream,
                       Qh, Ql, Kh, Kl, attn, candv, candi);
    hipLaunchKernelGGL(merge_kernel, dim3(B_), dim3(256), 0, stream,
                       attn, candv, candi, diag, tidx, tval);

    // Hd GEMM after attn: output aliases the (now dead) Q buffers
    hipLaunchKernelGGL(gemm_mfma_kernel, gg, dim3(256), 0, stream,
                       X, Bgh, Bgl, (const float*)nullptr, Hd, (ushort*)nullptr, (ushort*)nullptr, 0);

    hipLaunchKernelGGL(out_kernel, dim3(M_), dim3(256), 0, stream,
                       Hd, diag, tidx, tval, bgc, out);
}

// Round 7
// 614.705 us; speedup vs baseline: 4.1226x; 1.8055x over previous
//
#include <hip/hip_runtime.h>

#define B_  32
#define N_  512
#define D_  791
#define H_  7
#define DK_ 113
#define M_  (B_*N_)
#define KP_ 800              // K-dim padded to mult of 32
#define DP_ 896              // per-head-padded col dim: 7 heads x 128

typedef __attribute__((ext_vector_type(8))) short bf16x8;
typedef __attribute__((ext_vector_type(4))) float f32x4;

// ---------------- bf16 split helpers (RNE) ----------------
__device__ __forceinline__ ushort f2bf_rn(float x) {
    uint u = __float_as_uint(x);
    uint r = (u + 0x7FFFu + ((u >> 16) & 1u)) >> 16;
    return (ushort)r;
}
__device__ __forceinline__ float bf2f(ushort h) {
    return __uint_as_float(((uint)h) << 16);
}
__device__ __forceinline__ void split_bf16(float x, ushort& h, ushort& l) {
    h = f2bf_rn(x);
    l = f2bf_rn(x - bf2f(h));
}

// ---------------- async global->LDS 16B helper ----------------
__device__ __forceinline__ void gload16(const void* g, void* l) {
    __builtin_amdgcn_global_load_lds(
        (const __attribute__((address_space(1))) void*)g,
        (__attribute__((address_space(3))) void*)l, 16, 0, 0);
}

// ---------- X -> split bf16 Xh/Xl [16384][800] (zero-pad K) ----------
__global__ __launch_bounds__(256)
void splitX_kernel(const float* __restrict__ X, ushort* __restrict__ Xh,
                   ushort* __restrict__ Xl)
{
    int g = blockIdx.x * 256 + threadIdx.x;       // 0 .. M_*100-1
    if (g >= M_ * 100) return;
    int row = g / 100, grp = g % 100;
    int k0 = grp * 8;
    float v[8];
    if (k0 + 8 <= D_) {
        const float* p = X + (size_t)row * D_ + k0;
        #pragma unroll
        for (int i = 0; i < 8; ++i) v[i] = p[i];
    } else {
        #pragma unroll
        for (int i = 0; i < 8; ++i) {
            int k = k0 + i;
            v[i] = (k < D_) ? X[(size_t)row * D_ + k] : 0.f;
        }
    }
    bf16x8 hv, lv;
    #pragma unroll
    for (int i = 0; i < 8; ++i) {
        ushort h, l; split_bf16(v[i], h, l);
        hv[i] = (short)h; lv[i] = (short)l;
    }
    *(bf16x8*)&Xh[(size_t)row * KP_ + k0] = hv;
    *(bf16x8*)&Xl[(size_t)row * KP_ + k0] = lv;
}

// ---------- W -> transposed/padded/split Bt[pc][k] ----------
__global__ __launch_bounds__(256)
void castWt_kernel(const float* __restrict__ W0, const float* __restrict__ W1,
                   const float* __restrict__ W2,
                   ushort* __restrict__ B0h, ushort* __restrict__ B0l,
                   ushort* __restrict__ B1h, ushort* __restrict__ B1l,
                   ushort* __restrict__ B2h, ushort* __restrict__ B2l)
{
    const int pc = blockIdx.x;                // 0..895
    const int w  = blockIdx.y;                // which weight
    const float* W = (w == 0) ? W0 : (w == 1) ? W1 : W2;
    ushort* Bh = (w == 0) ? B0h : (w == 1) ? B1h : B2h;
    ushort* Bl = (w == 0) ? B0l : (w == 1) ? B1l : B2l;
    int src;
    if (w == 2) src = (pc < D_) ? pc : -1;
    else { int hh = pc >> 7, off = pc & 127; src = (off < DK_) ? hh * DK_ + off : -1; }
    for (int k = threadIdx.x; k < KP_; k += 256) {
        float v = (src >= 0 && k < D_) ? W[(size_t)k * D_ + src] : 0.f;
        ushort h, l; split_bf16(v, h, l);
        Bh[(size_t)pc * KP_ + k] = h;
        Bl[(size_t)pc * KP_ + k] = l;
    }
}

// ======== m97-structure GEMM core (shared by QK and Hd kernels) ========
// 128x128 tile, 4 waves, split-bf16 3-term, global_load_lds staging with
// both-sides chunk swizzle q' = q ^ ((row>>1)&3)  (rule #21 involution).
// LDS per buffer: [128 rows][32 k] ushort, linear (64 B/row).
#define GEMM_STAGE(dstH, dstL, srcH, srcL, rowBase)                          \
    {                                                                        \
        _Pragma("unroll")                                                    \
        for (int j = 0; j < 2; ++j) {                                        \
            int c  = t + 256 * j;                                            \
            int r  = c >> 2, q = c & 3;                                      \
            int qs = q ^ ((r >> 1) & 3);                                     \
            size_t go = (size_t)(rowBase + r) * KP_ + k0 + qs * 8;           \
            ushort* lb_h = dstH + (size_t)((t & 192) + 256 * j) * 8;         \
            ushort* lb_l = dstL + (size_t)((t & 192) + 256 * j) * 8;         \
            gload16(&srcH[go], lb_h);                                        \
            gload16(&srcL[go], lb_l);                                        \
        }                                                                    \
    }

struct GemmAcc { f32x4 a[4][4]; };

__device__ __forceinline__ void gemm_core(
    const ushort* __restrict__ Xh, const ushort* __restrict__ Xl,
    const ushort* __restrict__ Bh, const ushort* __restrict__ Bl,
    int row0, int col0, int t, int wr, int wc, int fr, int kq,
    ushort* AsH, ushort* AsL, ushort* BsH, ushort* BsL, GemmAcc& acc)
{
    for (int k0 = 0; k0 < KP_; k0 += 32) {
        GEMM_STAGE(AsH, AsL, Xh, Xl, row0)
        GEMM_STAGE(BsH, BsL, Bh, Bl, col0)
        __syncthreads();                    // drains vmcnt before LDS reads

        bf16x8 aH[4], aL[4], bH[4], bL[4];
        #pragma unroll
        for (int m = 0; m < 4; ++m) {
            int r = wr * 64 + m * 16 + fr;
            int off = r * 32 + (kq ^ ((r >> 1) & 3)) * 8;
            aH[m] = *(const bf16x8*)&AsH[off];
            aL[m] = *(const bf16x8*)&AsL[off];
        }
        #pragma unroll
        for (int n = 0; n < 4; ++n) {
            int c = wc * 64 + n * 16 + fr;
            int off = c * 32 + (kq ^ ((c >> 1) & 3)) * 8;
            bH[n] = *(const bf16x8*)&BsH[off];
            bL[n] = *(const bf16x8*)&BsL[off];
        }
        #pragma unroll
        for (int m = 0; m < 4; ++m)
            #pragma unroll
            for (int n = 0; n < 4; ++n) {
                acc.a[m][n] = __builtin_amdgcn_mfma_f32_16x16x32_bf16(aH[m], bH[n], acc.a[m][n], 0, 0, 0);
                acc.a[m][n] = __builtin_amdgcn_mfma_f32_16x16x32_bf16(aH[m], bL[n], acc.a[m][n], 0, 0, 0);
                acc.a[m][n] = __builtin_amdgcn_mfma_f32_16x16x32_bf16(aL[m], bH[n], acc.a[m][n], 0, 0, 0);
            }
        __syncthreads();                    // LDS safe for next stage
    }
}

// -------- fused Q+K GEMM: grid (14,128), XCD-chunked swizzle --------
__global__ __launch_bounds__(256)
void gemm_qk_kernel(const ushort* __restrict__ Xh, const ushort* __restrict__ Xl,
                    const ushort* __restrict__ Bqh, const ushort* __restrict__ Bql,
                    const ushort* __restrict__ Bkh, const ushort* __restrict__ Bkl,
                    const float* __restrict__ bq, const float* __restrict__ bk,
                    ushort* __restrict__ Qh, ushort* __restrict__ Ql,
                    ushort* __restrict__ Kh, ushort* __restrict__ Kl)
{
    __shared__ ushort AsH[128*32], AsL[128*32], BsH[128*32], BsL[128*32];
    const int flat = blockIdx.x + 14 * blockIdx.y;        // 0..1791
    const int nid  = (flat & 7) * 224 + (flat >> 3);      // XCD-chunked
    const int by = nid / 14, bx = nid % 14;
    const int w = bx / 7, ct = bx % 7;
    const int row0 = by * 128, col0 = ct * 128;
    const ushort* Bh = w ? Bkh : Bqh;
    const ushort* Bl = w ? Bkl : Bql;
    const float* bias = w ? bk : bq;
    ushort* Ch = w ? Kh : Qh;
    ushort* Cl = w ? Kl : Ql;

    const int t = threadIdx.x, lane = t & 63, wid = t >> 6;
    const int wr = wid >> 1, wc = wid & 1;
    const int fr = lane & 15, kq = lane >> 4;

    GemmAcc acc;
    #pragma unroll
    for (int m = 0; m < 4; ++m)
        #pragma unroll
        for (int n = 0; n < 4; ++n) acc.a[m][n] = (f32x4){0.f,0.f,0.f,0.f};

    gemm_core(Xh, Xl, Bh, Bl, row0, col0, t, wr, wc, fr, kq,
              AsH, AsL, BsH, BsL, acc);

    // epilogue: split-bf16 padded output [row][896]
    const int orow = kq * 4;
    #pragma unroll
    for (int n = 0; n < 4; ++n) {
        int pc = col0 + wc * 64 + n * 16 + fr;
        int hh = pc >> 7, off = pc & 127;
        float bb = (off < DK_) ? bias[hh * DK_ + off] : 0.f;
        #pragma unroll
        for (int m = 0; m < 4; ++m)
            #pragma unroll
            for (int j = 0; j < 4; ++j) {
                int gr = row0 + wr * 64 + m * 16 + orow + j;
                float v = acc.a[m][n][j] + bb;
                ushort h, l; split_bf16(v, h, l);
                Ch[(size_t)gr * DP_ + pc] = h;
                Cl[(size_t)gr * DP_ + pc] = l;
            }
    }
}

// -------- Hd GEMM: grid (7,128), fp32 packed output --------
__global__ __launch_bounds__(256)
void gemm_hd_kernel(const ushort* __restrict__ Xh, const ushort* __restrict__ Xl,
                    const ushort* __restrict__ Bgh, const ushort* __restrict__ Bgl,
                    float* __restrict__ Cf)
{
    __shared__ ushort AsH[128*32], AsL[128*32], BsH[128*32], BsL[128*32];
    const int flat = blockIdx.x + 7 * blockIdx.y;         // 0..895
    const int nid  = (flat & 7) * 112 + (flat >> 3);
    const int by = nid / 7, bx = nid % 7;
    const int row0 = by * 128, col0 = bx * 128;

    const int t = threadIdx.x, lane = t & 63, wid = t >> 6;
    const int wr = wid >> 1, wc = wid & 1;
    const int fr = lane & 15, kq = lane >> 4;

    GemmAcc acc;
    #pragma unroll
    for (int m = 0; m < 4; ++m)
        #pragma unroll
        for (int n = 0; n < 4; ++n) acc.a[m][n] = (f32x4){0.f,0.f,0.f,0.f};

    gemm_core(Xh, Xl, Bgh, Bgl, row0, col0, t, wr, wc, fr, kq,
              AsH, AsL, BsH, BsL, acc);

    const int orow = kq * 4;
    #pragma unroll
    for (int n = 0; n < 4; ++n) {
        int gc = col0 + wc * 64 + n * 16 + fr;
        if (gc < D_) {
            #pragma unroll
            for (int m = 0; m < 4; ++m)
                #pragma unroll
                for (int j = 0; j < 4; ++j) {
                    int gr = row0 + wr * 64 + m * 16 + orow + j;
                    Cf[(size_t)gr * D_ + gc] = acc.a[m][n][j];
                }
        }
    }
}

// -------- MFMA attention + fused per-block top-2 candidates --------
__global__ __launch_bounds__(256, 2)
void attn_mfma(const ushort* __restrict__ Qh, const ushort* __restrict__ Ql,
               const ushort* __restrict__ Kh, const ushort* __restrict__ Kl,
               float* __restrict__ attn, float* __restrict__ candv,
               int* __restrict__ candi)
{
    __shared__ ushort KsH[512*32];   // 32 KB, XOR-swizzled
    __shared__ ushort KsL[512*32];   // 32 KB
    __shared__ float redA[4][32];
    __shared__ float redB[4][32];
    __shared__ float wv[8]; __shared__ int wi[8];

    const int t = threadIdx.x, lane = t & 63, w = t >> 6;
    const int bid = blockIdx.x;
    const int swz = (bid & 7) * 64 + (bid >> 3);   // XCD-contiguous batches
    const int b = swz >> 4, r0 = (swz & 15) * 32;
    const int fr = lane & 15, kg = (lane >> 4) * 8;
    const float scale = 0.09407208683f;            // 1/sqrt(113)

    f32x4 accA[2][8];
    #pragma unroll
    for (int m = 0; m < 2; ++m)
        #pragma unroll
        for (int n = 0; n < 8; ++n) accA[m][n] = (f32x4){0.f,0.f,0.f,0.f};

    for (int h = 0; h < H_; ++h) {
        f32x4 S[2][8];
        #pragma unroll
        for (int m = 0; m < 2; ++m)
            #pragma unroll
            for (int n = 0; n < 8; ++n) S[m][n] = (f32x4){0.f,0.f,0.f,0.f};

        #pragma unroll
        for (int kk = 0; kk < 4; ++kk) {
            bf16x8 qH[2], qL[2];
            #pragma unroll
            for (int m = 0; m < 2; ++m) {
                size_t qo = (size_t)(b * N_ + r0 + m * 16 + fr) * DP_ + h * 128 + kk * 32 + kg;
                qH[m] = *(const bf16x8*)&Qh[qo];
                qL[m] = *(const bf16x8*)&Ql[qo];
            }
            #pragma unroll
            for (int i = 0; i < 8; ++i) {
                int g = t + 256 * i;
                int key = g >> 2, c8 = (g & 3) * 8;
                size_t go = (size_t)(b * N_ + key) * DP_ + h * 128 + kk * 32 + c8;
                int lo = key * 32 + (c8 ^ ((key & 3) * 8));
                *(bf16x8*)&KsH[lo] = *(const bf16x8*)&Kh[go];
                *(bf16x8*)&KsL[lo] = *(const bf16x8*)&Kl[go];
            }
            __syncthreads();
            #pragma unroll
            for (int n = 0; n < 8; ++n) {
                int key = w * 128 + n * 16 + fr;
                int lo = key * 32 + (kg ^ ((key & 3) * 8));
                bf16x8 bH = *(const bf16x8*)&KsH[lo];
                bf16x8 bL = *(const bf16x8*)&KsL[lo];
                #pragma unroll
                for (int m = 0; m < 2; ++m) {
                    S[m][n] = __builtin_amdgcn_mfma_f32_16x16x32_bf16(qH[m], bH, S[m][n], 0, 0, 0);
                    S[m][n] = __builtin_amdgcn_mfma_f32_16x16x32_bf16(qH[m], bL, S[m][n], 0, 0, 0);
                    S[m][n] = __builtin_amdgcn_mfma_f32_16x16x32_bf16(qL[m], bH, S[m][n], 0, 0, 0);
                }
            }
            __syncthreads();
        }

        // ---- softmax over keys for each of the 32 rows ----
        float fm[2][4];
        #pragma unroll
        for (int m = 0; m < 2; ++m)
            #pragma unroll
            for (int j = 0; j < 4; ++j) {
                float mx = -1e30f;
                #pragma unroll
                for (int n = 0; n < 8; ++n) {
                    S[m][n][j] *= scale;
                    mx = fmaxf(mx, S[m][n][j]);
                }
                #pragma unroll
                for (int d = 1; d < 16; d <<= 1) mx = fmaxf(mx, __shfl_xor(mx, d));
                fm[m][j] = mx;
            }
        if ((lane & 15) == 0) {
            #pragma unroll
            for (int m = 0; m < 2; ++m)
                #pragma unroll
                for (int j = 0; j < 4; ++j)
                    redA[w][m * 16 + (lane >> 4) * 4 + j] = fm[m][j];
        }
        __syncthreads();
        #pragma unroll
        for (int m = 0; m < 2; ++m)
            #pragma unroll
            for (int j = 0; j < 4; ++j) {
                int q = m * 16 + (lane >> 4) * 4 + j;
                float mx = redA[0][q];
                mx = fmaxf(mx, redA[1][q]);
                mx = fmaxf(mx, redA[2][q]);
                mx = fmaxf(mx, redA[3][q]);
                fm[m][j] = mx;
            }
        float sm[2][4];
        #pragma unroll
        for (int m = 0; m < 2; ++m)
            #pragma unroll
            for (int j = 0; j < 4; ++j) {
                float s = 0.f;
                #pragma unroll
                for (int n = 0; n < 8; ++n) {
                    float e = __expf(S[m][n][j] - fm[m][j]);
                    S[m][n][j] = e; s += e;
                }
                #pragma unroll
                for (int d = 1; d < 16; d <<= 1) s += __shfl_xor(s, d);
                sm[m][j] = s;
            }
        if ((lane & 15) == 0) {
            #pragma unroll
            for (int m = 0; m < 2; ++m)
                #pragma unroll
                for (int j = 0; j < 4; ++j)
                    redB[w][m * 16 + (lane >> 4) * 4 + j] = sm[m][j];
        }
        __syncthreads();
        #pragma unroll
        for (int m = 0; m < 2; ++m)
            #pragma unroll
            for (int j = 0; j < 4; ++j) {
                int q = m * 16 + (lane >> 4) * 4 + j;
                float s = redB[0][q] + redB[1][q] + redB[2][q] + redB[3][q];
                float rinv = 1.f / s;
                #pragma unroll
                for (int n = 0; n < 8; ++n)
                    accA[m][n][j] += S[m][n][j] * rinv;
            }
        __syncthreads();   // redA/redB safe for next head
    }

    // ---- write attn rows ----
    float* ab = attn + (size_t)b * N_ * N_;
    #pragma unroll
    for (int m = 0; m < 2; ++m)
        #pragma unroll
        for (int j = 0; j < 4; ++j) {
            int row = r0 + m * 16 + (lane >> 4) * 4 + j;
            float* ar = ab + (size_t)row * N_;
            #pragma unroll
            for (int n = 0; n < 8; ++n)
                ar[w * 128 + n * 16 + fr] = accA[m][n][j];
        }

    // ---- block-local top-2 over register values ----
    float v1 = -1e30f, v2 = -1e30f; int i1 = 0, i2 = 0;
    #pragma unroll
    for (int m = 0; m < 2; ++m)
        #pragma unroll
        for (int n = 0; n < 8; ++n)
            #pragma unroll
            for (int j = 0; j < 4; ++j) {
                float v = accA[m][n][j];
                int row = r0 + m * 16 + (lane >> 4) * 4 + j;
                int col = w * 128 + n * 16 + fr;
                int idx = row * N_ + col;
                if (v > v1)      { v2 = v1; i2 = i1; v1 = v; i1 = idx; }
                else if (v > v2) { v2 = v;  i2 = idx; }
            }
    #pragma unroll
    for (int d = 1; d < 64; d <<= 1) {
        float ov1 = __shfl_xor(v1, d); int oi1 = __shfl_xor(i1, d);
        float ov2 = __shfl_xor(v2, d); int oi2 = __shfl_xor(i2, d);
        if (ov1 > v1)      { v2 = v1; i2 = i1; v1 = ov1; i1 = oi1; }
        else if (ov1 > v2) { v2 = ov1; i2 = oi1; }
        if (ov2 > v1)      { v2 = v1; i2 = i1; v1 = ov2; i1 = oi2; }
        else if (ov2 > v2) { v2 = ov2; i2 = oi2; }
    }
    if (lane == 0) { wv[w*2] = v1; wi[w*2] = i1; wv[w*2+1] = v2; wi[w*2+1] = i2; }
    __syncthreads();
    if (t == 0) {
        float g1 = -1e30f, g2 = -1e30f; int gi1 = 0, gi2 = 0;
        for (int e = 0; e < 8; ++e) {
            float v = wv[e]; int ii = wi[e];
            if (v > g1)      { g2 = g1; gi2 = gi1; g1 = v; gi1 = ii; }
            else if (v > g2) { g2 = v; gi2 = ii; }
        }
        int cb = (b * 16 + (swz & 15)) * 2;
        candv[cb] = g1; candi[cb] = gi1;
        candv[cb+1] = g2; candi[cb+1] = gi2;
    }
}

// -------- merge per-batch candidates + extract diag + gather transposes -----
__global__ __launch_bounds__(256)
void merge_kernel(const float* __restrict__ attn, const float* __restrict__ candv,
                  const int* __restrict__ candi, float* __restrict__ diag,
                  int* __restrict__ tidx, float* __restrict__ tval)
{
    const int b = blockIdx.x, t = threadIdx.x;
    const float* ab = attn + (size_t)b * N_ * N_;
    for (int n = t; n < N_; n += 256) diag[b * N_ + n] = ab[(size_t)n * N_ + n];
    if (t == 0) {
        float v1 = -1e30f, v2 = -1e30f; int i1 = 0, i2 = 0;
        for (int s = 0; s < 32; ++s) {
            float v = candv[b * 32 + s]; int ii = candi[b * 32 + s];
            if (v > v1)      { v2 = v1; i2 = i1; v1 = v; i1 = ii; }
            else if (v > v2) { v2 = v; i2 = ii; }
        }
        int r1 = i1 / N_, c1 = i1 % N_;
        int r2 = i2 / N_, c2 = i2 % N_;
        tidx[b*4+0] = r1; tidx[b*4+1] = c1; tidx[b*4+2] = r2; tidx[b*4+3] = c2;
        tval[b*4+0] = ab[(size_t)r1 * N_ + c1];
        tval[b*4+1] = ab[(size_t)c1 * N_ + r1];
        tval[b*4+2] = ab[(size_t)r2 * N_ + c2];
        tval[b*4+3] = ab[(size_t)c2 * N_ + r2];
    }
}

// -------- sparse graph-conv epilogue --------
__global__ __launch_bounds__(256)
void out_kernel(const float* __restrict__ Hd, const float* __restrict__ diag,
                const int* __restrict__ tidx, const float* __restrict__ tval,
                const float* __restrict__ bgc, float* __restrict__ out)
{
    const int bn = blockIdx.x;
    const int b = bn >> 9, n = bn & 511;
    const int t = threadIdx.x;

    const int r1 = tidx[b*4+0], c1 = tidx[b*4+1];
    const int r2 = tidx[b*4+2], c2 = tidx[b*4+3];

    int   mc[4]; float mv[4]; int nc = 0;
    if (r1 != c1) {
        if (n == r1) { mc[nc] = c1; mv[nc] = tval[b*4+0]; ++nc; }
        if (n == c1) { mc[nc] = r1; mv[nc] = tval[b*4+1]; ++nc; }
    }
    if (r2 != c2) {
        if (n == r2) { mc[nc] = c2; mv[nc] = tval[b*4+2]; ++nc; }
        if (n == c2) { mc[nc] = r2; mv[nc] = tval[b*4+3]; ++nc; }
    }
    const float dg = diag[bn];
    float denom = dg + 1.0f;
    for (int i = 0; i < nc; ++i) denom += mv[i];
    const float rd = 1.f / denom;

    const float* hn = Hd + (size_t)bn * D_;
    for (int d = t; d < D_; d += 256) {
        float acc = dg * hn[d];
        for (int i = 0; i < nc; ++i)
            acc += mv[i] * Hd[(size_t)(b * N_ + mc[i]) * D_ + d];
        float o = acc * rd + bgc[d];
        out[(size_t)bn * D_ + d] = fmaxf(o, 0.f);
    }
}

extern "C" void kernel_launch(void* const* d_in, const int* in_sizes, int n_in,
                              void* d_out, int out_size, void* d_ws, size_t ws_size,
                              hipStream_t stream)
{
    const float* X   = (const float*)d_in[0];
    const float* Wq  = (const float*)d_in[1];
    const float* bq  = (const float*)d_in[2];
    const float* Wk  = (const float*)d_in[3];
    const float* bk  = (const float*)d_in[4];
    const float* Wgc = (const float*)d_in[5];
    const float* bgc = (const float*)d_in[6];
    float* out = (float*)d_out;

    ushort* wsu = (ushort*)d_ws;
    const size_t MDP = (size_t)M_ * DP_;          // 14,680,064
    const size_t MKP = (size_t)M_ * KP_;          // 13,107,200
    ushort* Qh = wsu;
    ushort* Ql = wsu + MDP;
    ushort* Kh = wsu + 2 * MDP;
    ushort* Kl = wsu + 3 * MDP;
    ushort* Bt = wsu + 4 * MDP;
    const size_t BSZ = (size_t)DP_ * KP_;         // 716,800
    ushort* Bqh = Bt;            ushort* Bql = Bt + BSZ;
    ushort* Bkh = Bt + 2 * BSZ;  ushort* Bkl = Bt + 3 * BSZ;
    ushort* Bgh = Bt + 4 * BSZ;  ushort* Bgl = Bt + 5 * BSZ;
    ushort* Xh  = Bt + 6 * BSZ;                   // MKP ushorts (26.2 MB)
    float* diag  = (float*)(Xh + MKP);            // M_ floats
    int*   tidx  = (int*)(diag + M_);             // 128
    float* tval  = (float*)(tidx + 128);          // 128
    float* candv = tval + 128;                    // 1024
    int*   candi = (int*)(candv + 1024);          // 1024
    // Xl parked in d_out: dead once GEMMs complete; attn overwrites it later.
    ushort* Xl  = (ushort*)d_out;
    float* Hd   = (float*)d_ws;                   // aliases Qh/Ql AFTER attn
    float* attn = out;                            // d_out as attn scratch

    hipLaunchKernelGGL(splitX_kernel, dim3((M_ * 100 + 255) / 256), dim3(256), 0, stream,
                       X, Xh, Xl);
    hipLaunchKernelGGL(castWt_kernel, dim3(DP_, 3), dim3(256), 0, stream,
                       Wq, Wk, Wgc, Bqh, Bql, Bkh, Bkl, Bgh, Bgl);

    hipLaunchKernelGGL(gemm_qk_kernel, dim3(14, 128), dim3(256), 0, stream,
                       Xh, Xl, Bqh, Bql, Bkh, Bkl, bq, bk, Qh, Ql, Kh, Kl);

    hipLaunchKernelGGL(attn_mfma, dim3(512), dim3(256), 0, stream,
                       Qh, Ql, Kh, Kl, attn, candv, candi);
    hipLaunchKernelGGL(merge_kernel, dim3(B_), dim3(256), 0, stream,
                       attn, candv, candi, diag, tidx, tval);

    // NOTE: gemm_hd reads Xh(ws)+Xl(d_out's head). Xl region overlaps attn
    // scratch — but attn (33.5 MB) starts at d_out+0 too. Xl must survive
    // until here, so re-split it? No: attn_mfma already overwrote d_out.
    // Therefore re-create Xl before gemm_hd via a second splitX into the
    // tail of d_ws is impossible (no space). Instead: run gemm_hd BEFORE
    // attn — Hd aliases Qh/Ql which attn still needs. Resolution: Hd GEMM
    // runs here but writes into Kh/Kl space (dead after attn)? Also dead
    // only after attn. => run gemm_hd BEFORE attn into separate space is
    // impossible; so instead gemm_hd runs BEFORE attn and writes Hd into
    // the d_ws tail... no space either. Final resolution used below:
    // gemm_hd runs immediately after gemm_qk (Xl still intact, attn not
    // yet run) and writes fp32 Hd OVER Xh+Bt? Xh needed by gemm_hd itself.
    // => Hd goes to its own slot: we place it over Bt+Xh AFTER gemm_hd
    // reads them? Same-dispatch read/write alias across blocks = race.
    // SAFE layout: Hd = Kh/Kl region is wrong (attn needs K).
    // Chosen: gemm_hd writes Hd interleaved into d_out TAIL (18.3 MB) +
    // ... insufficient. See actual call below: gemm_hd runs after gemm_qk,
    // Hd lands in the 58.7 MB Qh/Ql slot? attn needs Q. Dead end at 156MB
    // — EXCEPT: attn only needs Q/K until it finishes; Hd only needed by
    // out_kernel. d_out tail (4.57M floats) + diag slack can't hold it.
    // => keep original order (attn first), and re-split Xl for gemm_hd
    // from X directly: gemm_hd uses a variant reading fp32 X with on-the-
    // fly hi (cheap) — NO. Simplest correct: splitXl2 kernel re-generates
    // Xl into d_out AFTER attn+merge (attn data already consumed: merge
    // extracted diag/top2; out_kernel needs only diag/tidx/tval/Hd).
    hipLaunchKernelGGL(splitX_kernel, dim3((M_ * 100 + 255) / 256), dim3(256), 0, stream,
                       X, Xh, Xl);   // regenerate Xl (d_out) post-attn; Xh rewrite is harmless
    hipLaunchKernelGGL(gemm_hd_kernel, dim3(7, 128), dim3(256), 0, stream,
                       Xh, Xl, Bgh, Bgl, Hd);

    hipLaunchKernelGGL(out_kernel, dim3(M_), dim3(256), 0, stream,
                       Hd, diag, tidx, tval, bgc, out);
}

// Round 8
// 600.410 us; speedup vs baseline: 4.2208x; 1.0238x over previous
//
#include <hip/hip_runtime.h>

#define B_  32
#define N_  512
#define D_  791
#define H_  7
#define DK_ 113
#define M_  (B_*N_)
#define KP_ 800              // K-dim padded to mult of 32
#define DP_ 896              // per-head-padded col dim: 7 heads x 128
#define NKT 25               // KP_/32 K-tiles

typedef __attribute__((ext_vector_type(8))) short bf16x8;
typedef __attribute__((ext_vector_type(4))) float f32x4;

// ---------------- bf16 split helpers (RNE) ----------------
__device__ __forceinline__ ushort f2bf_rn(float x) {
    uint u = __float_as_uint(x);
    uint r = (u + 0x7FFFu + ((u >> 16) & 1u)) >> 16;
    return (ushort)r;
}
__device__ __forceinline__ float bf2f(ushort h) {
    return __uint_as_float(((uint)h) << 16);
}
__device__ __forceinline__ void split_bf16(float x, ushort& h, ushort& l) {
    h = f2bf_rn(x);
    l = f2bf_rn(x - bf2f(h));
}

// ---------------- async global->LDS 16B helper ----------------
__device__ __forceinline__ void gload16(const void* g, void* l) {
    __builtin_amdgcn_global_load_lds(
        (const __attribute__((address_space(1))) void*)g,
        (__attribute__((address_space(3))) void*)l, 16, 0, 0);
}

// ---------- X -> split bf16 Xh/Xl [16384][800] (zero-pad K) ----------
__global__ __launch_bounds__(256)
void splitX_kernel(const float* __restrict__ X, ushort* __restrict__ Xh,
                   ushort* __restrict__ Xl)
{
    int g = blockIdx.x * 256 + threadIdx.x;       // 0 .. M_*100-1
    if (g >= M_ * 100) return;
    int row = g / 100, grp = g % 100;
    int k0 = grp * 8;
    float v[8];
    if (k0 + 8 <= D_) {
        const float* p = X + (size_t)row * D_ + k0;
        #pragma unroll
        for (int i = 0; i < 8; ++i) v[i] = p[i];
    } else {
        #pragma unroll
        for (int i = 0; i < 8; ++i) {
            int k = k0 + i;
            v[i] = (k < D_) ? X[(size_t)row * D_ + k] : 0.f;
        }
    }
    bf16x8 hv, lv;
    #pragma unroll
    for (int i = 0; i < 8; ++i) {
        ushort h, l; split_bf16(v[i], h, l);
        hv[i] = (short)h; lv[i] = (short)l;
    }
    *(bf16x8*)&Xh[(size_t)row * KP_ + k0] = hv;
    *(bf16x8*)&Xl[(size_t)row * KP_ + k0] = lv;
}

// ---------- W -> transposed/padded/split Bt[pc][k], 32x32 LDS tiles ----------
__global__ __launch_bounds__(256)
void castWt_kernel(const float* __restrict__ W0, const float* __restrict__ W1,
                   const float* __restrict__ W2,
                   ushort* __restrict__ B0h, ushort* __restrict__ B0l,
                   ushort* __restrict__ B1h, ushort* __restrict__ B1l,
                   ushort* __restrict__ B2h, ushort* __restrict__ B2l)
{
    __shared__ ushort WsH[32][34], WsL[32][34];
    const int pc0 = blockIdx.x * 32;              // 0..895 step 32
    const int k0  = blockIdx.y * 32;              // 0..799 step 32
    const int w   = blockIdx.z;
    const float* W = (w == 0) ? W0 : (w == 1) ? W1 : W2;
    ushort* Bh = (w == 0) ? B0h : (w == 1) ? B1h : B2h;
    ushort* Bl = (w == 0) ? B0l : (w == 1) ? B1l : B2l;
    const int tx = threadIdx.x & 31, ty = threadIdx.x >> 5;   // 32 x 8

    // phase 1: coalesced read W[k][src(pc)], split, store transposed-ready
    #pragma unroll
    for (int r = 0; r < 4; ++r) {
        int kl = ty + 8 * r, k = k0 + kl;
        int pc = pc0 + tx;
        int src;
        if (w == 2) src = (pc < D_) ? pc : -1;
        else { int hh = pc >> 7, off = pc & 127; src = (off < DK_) ? hh * DK_ + off : -1; }
        float v = (src >= 0 && k < D_) ? W[(size_t)k * D_ + src] : 0.f;
        ushort h, l; split_bf16(v, h, l);
        WsH[tx][kl] = h; WsL[tx][kl] = l;
    }
    __syncthreads();
    // phase 2: coalesced write Bt[pc][k]
    #pragma unroll
    for (int r = 0; r < 4; ++r) {
        int pcl = ty + 8 * r, pc = pc0 + pcl;
        int k = k0 + tx;
        Bh[(size_t)pc * KP_ + k] = WsH[pcl][tx];
        Bl[(size_t)pc * KP_ + k] = WsL[pcl][tx];
    }
}

// ======== double-buffered GEMM staging/compute building blocks ========
// LDS tile [128 rows][32 k] ushort, linear; both-sides chunk swizzle
// q' = q ^ ((row>>1)&3) applied to the GLOBAL source and the LDS read.
#define STAGE_PAIR(dH, dL, srcH, srcL, rowBase, kk0)                         \
    {                                                                        \
        _Pragma("unroll")                                                    \
        for (int j = 0; j < 2; ++j) {                                        \
            int c  = t + 256 * j;                                            \
            int r  = c >> 2, q = c & 3;                                      \
            int qs = q ^ ((r >> 1) & 3);                                     \
            size_t go = (size_t)(rowBase + r) * KP_ + (kk0) + qs * 8;        \
            int lofs = ((t & 192) + 256 * j) * 8;                            \
            gload16(&srcH[go], (dH) + lofs);                                 \
            gload16(&srcL[go], (dL) + lofs);                                 \
        }                                                                    \
    }
#define STAGE_ONE(dH, srcH, rowBase, kk0)                                    \
    {                                                                        \
        _Pragma("unroll")                                                    \
        for (int j = 0; j < 2; ++j) {                                        \
            int c  = t + 256 * j;                                            \
            int r  = c >> 2, q = c & 3;                                      \
            int qs = q ^ ((r >> 1) & 3);                                     \
            size_t go = (size_t)(rowBase + r) * KP_ + (kk0) + qs * 8;        \
            int lofs = ((t & 192) + 256 * j) * 8;                            \
            gload16(&srcH[go], (dH) + lofs);                                 \
        }                                                                    \
    }

struct GemmAcc { f32x4 a[4][4]; };

// -------- fused Q+K GEMM: grid (14,128), XCD-chunked, dbuf 2-phase --------
__global__ __launch_bounds__(256)
void gemm_qk_kernel(const ushort* __restrict__ Xh, const ushort* __restrict__ Xl,
                    const ushort* __restrict__ Bqh, const ushort* __restrict__ Bql,
                    const ushort* __restrict__ Bkh, const ushort* __restrict__ Bkl,
                    const float* __restrict__ bq, const float* __restrict__ bk,
                    ushort* __restrict__ Qh, ushort* __restrict__ Ql,
                    ushort* __restrict__ Kh, ushort* __restrict__ Kl)
{
    __shared__ ushort AsH[2][128*32], AsL[2][128*32];
    __shared__ ushort BsH[2][128*32], BsL[2][128*32];
    const int flat = blockIdx.x + 14 * blockIdx.y;        // 0..1791
    const int nid  = (flat & 7) * 224 + (flat >> 3);      // XCD-chunked
    const int by = nid / 14, bx = nid % 14;
    const int w = bx / 7, ct = bx % 7;
    const int row0 = by * 128, col0 = ct * 128;
    const ushort* Bh = w ? Bkh : Bqh;
    const ushort* Bl = w ? Bkl : Bql;
    const float* bias = w ? bk : bq;
    ushort* Ch = w ? Kh : Qh;
    ushort* Cl = w ? Kl : Ql;

    const int t = threadIdx.x, lane = t & 63, wid = t >> 6;
    const int wr = wid >> 1, wc = wid & 1;
    const int fr = lane & 15, kq = lane >> 4;

    GemmAcc acc;
    #pragma unroll
    for (int m = 0; m < 4; ++m)
        #pragma unroll
        for (int n = 0; n < 4; ++n) acc.a[m][n] = (f32x4){0.f,0.f,0.f,0.f};

    STAGE_PAIR(AsH[0], AsL[0], Xh, Xl, row0, 0)
    STAGE_PAIR(BsH[0], BsL[0], Bh, Bl, col0, 0)
    __syncthreads();                                      // drains vmcnt(0)

    for (int kt = 0; kt < NKT; ++kt) {
        const int cur = kt & 1;
        if (kt + 1 < NKT) {                               // prefetch next tile
            STAGE_PAIR(AsH[cur^1], AsL[cur^1], Xh, Xl, row0, (kt+1)*32)
            STAGE_PAIR(BsH[cur^1], BsL[cur^1], Bh, Bl, col0, (kt+1)*32)
        }
        bf16x8 aH[4], aL[4], bH[4], bL[4];
        #pragma unroll
        for (int m = 0; m < 4; ++m) {
            int r = wr * 64 + m * 16 + fr;
            int off = r * 32 + (kq ^ ((r >> 1) & 3)) * 8;
            aH[m] = *(const bf16x8*)&AsH[cur][off];
            aL[m] = *(const bf16x8*)&AsL[cur][off];
        }
        #pragma unroll
        for (int n = 0; n < 4; ++n) {
            int c = wc * 64 + n * 16 + fr;
            int off = c * 32 + (kq ^ ((c >> 1) & 3)) * 8;
            bH[n] = *(const bf16x8*)&BsH[cur][off];
            bL[n] = *(const bf16x8*)&BsL[cur][off];
        }
        #pragma unroll
        for (int m = 0; m < 4; ++m)
            #pragma unroll
            for (int n = 0; n < 4; ++n) {
                acc.a[m][n] = __builtin_amdgcn_mfma_f32_16x16x32_bf16(aH[m], bH[n], acc.a[m][n], 0, 0, 0);
                acc.a[m][n] = __builtin_amdgcn_mfma_f32_16x16x32_bf16(aH[m], bL[n], acc.a[m][n], 0, 0, 0);
                acc.a[m][n] = __builtin_amdgcn_mfma_f32_16x16x32_bf16(aL[m], bH[n], acc.a[m][n], 0, 0, 0);
            }
        __syncthreads();            // drains next-tile vmcnt + joins waves
    }

    // epilogue: split-bf16 padded output [row][896]
    const int orow = kq * 4;
    #pragma unroll
    for (int n = 0; n < 4; ++n) {
        int pc = col0 + wc * 64 + n * 16 + fr;
        int hh = pc >> 7, off = pc & 127;
        float bb = (off < DK_) ? bias[hh * DK_ + off] : 0.f;
        #pragma unroll
        for (int m = 0; m < 4; ++m)
            #pragma unroll
            for (int j = 0; j < 4; ++j) {
                int gr = row0 + wr * 64 + m * 16 + orow + j;
                float v = acc.a[m][n][j] + bb;
                ushort h, l; split_bf16(v, h, l);
                Ch[(size_t)gr * DP_ + pc] = h;
                Cl[(size_t)gr * DP_ + pc] = l;
            }
    }
}

// -------- Hd GEMM (2-term Xh*(Wh+Wl)): grid (7,128), dbuf, fp32 out --------
__global__ __launch_bounds__(256)
void gemm_hd_kernel(const ushort* __restrict__ Xh,
                    const ushort* __restrict__ Bgh, const ushort* __restrict__ Bgl,
                    float* __restrict__ Cf)
{
    __shared__ ushort AsH[2][128*32];
    __shared__ ushort BsH[2][128*32], BsL[2][128*32];
    const int flat = blockIdx.x + 7 * blockIdx.y;         // 0..895
    const int nid  = (flat & 7) * 112 + (flat >> 3);
    const int by = nid / 7, bx = nid % 7;
    const int row0 = by * 128, col0 = bx * 128;

    const int t = threadIdx.x, lane = t & 63, wid = t >> 6;
    const int wr = wid >> 1, wc = wid & 1;
    const int fr = lane & 15, kq = lane >> 4;

    GemmAcc acc;
    #pragma unroll
    for (int m = 0; m < 4; ++m)
        #pragma unroll
        for (int n = 0; n < 4; ++n) acc.a[m][n] = (f32x4){0.f,0.f,0.f,0.f};

    STAGE_ONE(AsH[0], Xh, row0, 0)
    STAGE_PAIR(BsH[0], BsL[0], Bgh, Bgl, col0, 0)
    __syncthreads();

    for (int kt = 0; kt < NKT; ++kt) {
        const int cur = kt & 1;
        if (kt + 1 < NKT) {
            STAGE_ONE(AsH[cur^1], Xh, row0, (kt+1)*32)
            STAGE_PAIR(BsH[cur^1], BsL[cur^1], Bgh, Bgl, col0, (kt+1)*32)
        }
        bf16x8 aH[4], bH[4], bL[4];
        #pragma unroll
        for (int m = 0; m < 4; ++m) {
            int r = wr * 64 + m * 16 + fr;
            int off = r * 32 + (kq ^ ((r >> 1) & 3)) * 8;
            aH[m] = *(const bf16x8*)&AsH[cur][off];
        }
        #pragma unroll
        for (int n = 0; n < 4; ++n) {
            int c = wc * 64 + n * 16 + fr;
            int off = c * 32 + (kq ^ ((c >> 1) & 3)) * 8;
            bH[n] = *(const bf16x8*)&BsH[cur][off];
            bL[n] = *(const bf16x8*)&BsL[cur][off];
        }
        #pragma unroll
        for (int m = 0; m < 4; ++m)
            #pragma unroll
            for (int n = 0; n < 4; ++n) {
                acc.a[m][n] = __builtin_amdgcn_mfma_f32_16x16x32_bf16(aH[m], bH[n], acc.a[m][n], 0, 0, 0);
                acc.a[m][n] = __builtin_amdgcn_mfma_f32_16x16x32_bf16(aH[m], bL[n], acc.a[m][n], 0, 0, 0);
            }
        __syncthreads();
    }

    const int orow = kq * 4;
    #pragma unroll
    for (int n = 0; n < 4; ++n) {
        int gc = col0 + wc * 64 + n * 16 + fr;
        if (gc < D_) {
            #pragma unroll
            for (int m = 0; m < 4; ++m)
                #pragma unroll
                for (int j = 0; j < 4; ++j) {
                    int gr = row0 + wr * 64 + m * 16 + orow + j;
                    Cf[(size_t)gr * D_ + gc] = acc.a[m][n][j];
                }
        }
    }
}

// -------- MFMA attention + fused diag + per-block top-2 candidates --------
__global__ __launch_bounds__(256, 2)
void attn_mfma(const ushort* __restrict__ Qh, const ushort* __restrict__ Ql,
               const ushort* __restrict__ Kh, const ushort* __restrict__ Kl,
               float* __restrict__ attn, float* __restrict__ diag,
               float* __restrict__ candv, int* __restrict__ candi)
{
    __shared__ ushort KsH[512*32];   // 32 KB, XOR-swizzled
    __shared__ ushort KsL[512*32];   // 32 KB
    __shared__ float redA[4][32];
    __shared__ float redB[4][32];
    __shared__ float wv[8]; __shared__ int wi[8];

    const int t = threadIdx.x, lane = t & 63, w = t >> 6;
    const int bid = blockIdx.x;
    const int swz = (bid & 7) * 64 + (bid >> 3);   // XCD-contiguous batches
    const int b = swz >> 4, r0 = (swz & 15) * 32;
    const int fr = lane & 15, kg = (lane >> 4) * 8;
    const float scale = 0.09407208683f;            // 1/sqrt(113)

    f32x4 accA[2][8];
    #pragma unroll
    for (int m = 0; m < 2; ++m)
        #pragma unroll
        for (int n = 0; n < 8; ++n) accA[m][n] = (f32x4){0.f,0.f,0.f,0.f};

    for (int h = 0; h < H_; ++h) {
        f32x4 S[2][8];
        #pragma unroll
        for (int m = 0; m < 2; ++m)
            #pragma unroll
            for (int n = 0; n < 8; ++n) S[m][n] = (f32x4){0.f,0.f,0.f,0.f};

        #pragma unroll
        for (int kk = 0; kk < 4; ++kk) {
            bf16x8 qH[2], qL[2];
            #pragma unroll
            for (int m = 0; m < 2; ++m) {
                size_t qo = (size_t)(b * N_ + r0 + m * 16 + fr) * DP_ + h * 128 + kk * 32 + kg;
                qH[m] = *(const bf16x8*)&Qh[qo];
                qL[m] = *(const bf16x8*)&Ql[qo];
            }
            #pragma unroll
            for (int i = 0; i < 8; ++i) {
                int g = t + 256 * i;
                int key = g >> 2, c8 = (g & 3) * 8;
                size_t go = (size_t)(b * N_ + key) * DP_ + h * 128 + kk * 32 + c8;
                int lo = key * 32 + (c8 ^ ((key & 3) * 8));
                *(bf16x8*)&KsH[lo] = *(const bf16x8*)&Kh[go];
                *(bf16x8*)&KsL[lo] = *(const bf16x8*)&Kl[go];
            }
            __syncthreads();
            #pragma unroll
            for (int n = 0; n < 8; ++n) {
                int key = w * 128 + n * 16 + fr;
                int lo = key * 32 + (kg ^ ((key & 3) * 8));
                bf16x8 bH = *(const bf16x8*)&KsH[lo];
                bf16x8 bL = *(const bf16x8*)&KsL[lo];
                #pragma unroll
                for (int m = 0; m < 2; ++m) {
                    S[m][n] = __builtin_amdgcn_mfma_f32_16x16x32_bf16(qH[m], bH, S[m][n], 0, 0, 0);
                    S[m][n] = __builtin_amdgcn_mfma_f32_16x16x32_bf16(qH[m], bL, S[m][n], 0, 0, 0);
                    S[m][n] = __builtin_amdgcn_mfma_f32_16x16x32_bf16(qL[m], bH, S[m][n], 0, 0, 0);
                }
            }
            __syncthreads();
        }

        // ---- softmax over keys for each of the 32 rows ----
        float fm[2][4];
        #pragma unroll
        for (int m = 0; m < 2; ++m)
            #pragma unroll
            for (int j = 0; j < 4; ++j) {
                float mx = -1e30f;
                #pragma unroll
                for (int n = 0; n < 8; ++n) {
                    S[m][n][j] *= scale;
                    mx = fmaxf(mx, S[m][n][j]);
                }
                #pragma unroll
                for (int d = 1; d < 16; d <<= 1) mx = fmaxf(mx, __shfl_xor(mx, d));
                fm[m][j] = mx;
            }
        if ((lane & 15) == 0) {
            #pragma unroll
            for (int m = 0; m < 2; ++m)
                #pragma unroll
                for (int j = 0; j < 4; ++j)
                    redA[w][m * 16 + (lane >> 4) * 4 + j] = fm[m][j];
        }
        __syncthreads();
        #pragma unroll
        for (int m = 0; m < 2; ++m)
            #pragma unroll
            for (int j = 0; j < 4; ++j) {
                int q = m * 16 + (lane >> 4) * 4 + j;
                float mx = redA[0][q];
                mx = fmaxf(mx, redA[1][q]);
                mx = fmaxf(mx, redA[2][q]);
                mx = fmaxf(mx, redA[3][q]);
                fm[m][j] = mx;
            }
        float sm[2][4];
        #pragma unroll
        for (int m = 0; m < 2; ++m)
            #pragma unroll
            for (int j = 0; j < 4; ++j) {
                float s = 0.f;
                #pragma unroll
                for (int n = 0; n < 8; ++n) {
                    float e = __expf(S[m][n][j] - fm[m][j]);
                    S[m][n][j] = e; s += e;
                }
                #pragma unroll
                for (int d = 1; d < 16; d <<= 1) s += __shfl_xor(s, d);
                sm[m][j] = s;
            }
        if ((lane & 15) == 0) {
            #pragma unroll
            for (int m = 0; m < 2; ++m)
                #pragma unroll
                for (int j = 0; j < 4; ++j)
                    redB[w][m * 16 + (lane >> 4) * 4 + j] = sm[m][j];
        }
        __syncthreads();
        #pragma unroll
        for (int m = 0; m < 2; ++m)
            #pragma unroll
            for (int j = 0; j < 4; ++j) {
                int q = m * 16 + (lane >> 4) * 4 + j;
                float s = redB[0][q] + redB[1][q] + redB[2][q] + redB[3][q];
                float rinv = 1.f / s;
                #pragma unroll
                for (int n = 0; n < 8; ++n)
                    accA[m][n][j] += S[m][n][j] * rinv;
            }
        __syncthreads();   // redA/redB safe for next head
    }

    // ---- write attn rows + fused diagonal extraction ----
    float* ab = attn + (size_t)b * N_ * N_;
    #pragma unroll
    for (int m = 0; m < 2; ++m)
        #pragma unroll
        for (int j = 0; j < 4; ++j) {
            int row = r0 + m * 16 + (lane >> 4) * 4 + j;
            float* ar = ab + (size_t)row * N_;
            #pragma unroll
            for (int n = 0; n < 8; ++n) {
                int col = w * 128 + n * 16 + fr;
                ar[col] = accA[m][n][j];
                if (col == row) diag[b * N_ + row] = accA[m][n][j];
            }
        }

    // ---- block-local top-2 over register values ----
    float v1 = -1e30f, v2 = -1e30f; int i1 = 0, i2 = 0;
    #pragma unroll
    for (int m = 0; m < 2; ++m)
        #pragma unroll
        for (int n = 0; n < 8; ++n)
            #pragma unroll
            for (int j = 0; j < 4; ++j) {
                float v = accA[m][n][j];
                int row = r0 + m * 16 + (lane >> 4) * 4 + j;
                int col = w * 128 + n * 16 + fr;
                int idx = row * N_ + col;
                if (v > v1)      { v2 = v1; i2 = i1; v1 = v; i1 = idx; }
                else if (v > v2) { v2 = v;  i2 = idx; }
            }
    #pragma unroll
    for (int d = 1; d < 64; d <<= 1) {
        float ov1 = __shfl_xor(v1, d); int oi1 = __shfl_xor(i1, d);
        float ov2 = __shfl_xor(v2, d); int oi2 = __shfl_xor(i2, d);
        if (ov1 > v1)      { v2 = v1; i2 = i1; v1 = ov1; i1 = oi1; }
        else if (ov1 > v2) { v2 = ov1; i2 = oi1; }
        if (ov2 > v1)      { v2 = v1; i2 = i1; v1 = ov2; i1 = oi2; }
        else if (ov2 > v2) { v2 = ov2; i2 = oi2; }
    }
    if (lane == 0) { wv[w*2] = v1; wi[w*2] = i1; wv[w*2+1] = v2; wi[w*2+1] = i2; }
    __syncthreads();
    if (t == 0) {
        float g1 = -1e30f, g2 = -1e30f; int gi1 = 0, gi2 = 0;
        for (int e = 0; e < 8; ++e) {
            float v = wv[e]; int ii = wi[e];
            if (v > g1)      { g2 = g1; gi2 = gi1; g1 = v; gi1 = ii; }
            else if (v > g2) { g2 = v; gi2 = ii; }
        }
        int cb = (b * 16 + (swz & 15)) * 2;
        candv[cb] = g1; candi[cb] = gi1;
        candv[cb+1] = g2; candi[cb+1] = gi2;
    }
}

// -------- merge per-batch candidates + gather transposes --------
__global__ __launch_bounds__(64)
void merge_kernel(const float* __restrict__ attn, const float* __restrict__ candv,
                  const int* __restrict__ candi,
                  int* __restrict__ tidx, float* __restrict__ tval)
{
    const int b = blockIdx.x;
    if (threadIdx.x != 0) return;
    const float* ab = attn + (size_t)b * N_ * N_;
    float v1 = -1e30f, v2 = -1e30f; int i1 = 0, i2 = 0;
    for (int s = 0; s < 32; ++s) {
        float v = candv[b * 32 + s]; int ii = candi[b * 32 + s];
        if (v > v1)      { v2 = v1; i2 = i1; v1 = v; i1 = ii; }
        else if (v > v2) { v2 = v; i2 = ii; }
    }
    int r1 = i1 / N_, c1 = i1 % N_;
    int r2 = i2 / N_, c2 = i2 % N_;
    tidx[b*4+0] = r1; tidx[b*4+1] = c1; tidx[b*4+2] = r2; tidx[b*4+3] = c2;
    tval[b*4+0] = ab[(size_t)r1 * N_ + c1];
    tval[b*4+1] = ab[(size_t)c1 * N_ + r1];
    tval[b*4+2] = ab[(size_t)r2 * N_ + c2];
    tval[b*4+3] = ab[(size_t)c2 * N_ + r2];
}

// -------- sparse graph-conv epilogue --------
__global__ __launch_bounds__(256)
void out_kernel(const float* __restrict__ Hd, const float* __restrict__ diag,
                const int* __restrict__ tidx, const float* __restrict__ tval,
                const float* __restrict__ bgc, float* __restrict__ out)
{
    const int bn = blockIdx.x;
    const int b = bn >> 9, n = bn & 511;
    const int t = threadIdx.x;

    const int r1 = tidx[b*4+0], c1 = tidx[b*4+1];
    const int r2 = tidx[b*4+2], c2 = tidx[b*4+3];

    int   mc[4]; float mv[4]; int nc = 0;
    if (r1 != c1) {
        if (n == r1) { mc[nc] = c1; mv[nc] = tval[b*4+0]; ++nc; }
        if (n == c1) { mc[nc] = r1; mv[nc] = tval[b*4+1]; ++nc; }
    }
    if (r2 != c2) {
        if (n == r2) { mc[nc] = c2; mv[nc] = tval[b*4+2]; ++nc; }
        if (n == c2) { mc[nc] = r2; mv[nc] = tval[b*4+3]; ++nc; }
    }
    const float dg = diag[bn];
    float denom = dg + 1.0f;
    for (int i = 0; i < nc; ++i) denom += mv[i];
    const float rd = 1.f / denom;

    const float* hn = Hd + (size_t)bn * D_;
    for (int d = t; d < D_; d += 256) {
        float acc = dg * hn[d];
        for (int i = 0; i < nc; ++i)
            acc += mv[i] * Hd[(size_t)(b * N_ + mc[i]) * D_ + d];
        float o = acc * rd + bgc[d];
        out[(size_t)bn * D_ + d] = fmaxf(o, 0.f);
    }
}

extern "C" void kernel_launch(void* const* d_in, const int* in_sizes, int n_in,
                              void* d_out, int out_size, void* d_ws, size_t ws_size,
                              hipStream_t stream)
{
    const float* X   = (const float*)d_in[0];
    const float* Wq  = (const float*)d_in[1];
    const float* bq  = (const float*)d_in[2];
    const float* Wk  = (const float*)d_in[3];
    const float* bk  = (const float*)d_in[4];
    const float* Wgc = (const float*)d_in[5];
    const float* bgc = (const float*)d_in[6];
    float* out = (float*)d_out;

    ushort* wsu = (ushort*)d_ws;
    const size_t MDP = (size_t)M_ * DP_;          // 14,680,064
    const size_t MKP = (size_t)M_ * KP_;          // 13,107,200
    ushort* Qh = wsu;
    ushort* Ql = wsu + MDP;
    ushort* Kh = wsu + 2 * MDP;
    ushort* Kl = wsu + 3 * MDP;
    ushort* Bt = wsu + 4 * MDP;
    const size_t BSZ = (size_t)DP_ * KP_;         // 716,800
    ushort* Bqh = Bt;            ushort* Bql = Bt + BSZ;
    ushort* Bkh = Bt + 2 * BSZ;  ushort* Bkl = Bt + 3 * BSZ;
    ushort* Bgh = Bt + 4 * BSZ;  ushort* Bgl = Bt + 5 * BSZ;
    ushort* Xh  = Bt + 6 * BSZ;                   // MKP ushorts (26.2 MB)
    float* diag  = (float*)(Xh + MKP);            // M_ floats
    int*   tidx  = (int*)(diag + M_);             // 128
    float* tval  = (float*)(tidx + 128);          // 128
    float* candv = tval + 128;                    // 1024
    int*   candi = (int*)(candv + 1024);          // 1024
    // Xl parked in d_out: consumed by gemm_qk only; attn overwrites it later.
    ushort* Xl  = (ushort*)d_out;
    float* Hd   = (float*)d_ws;                   // aliases Qh/Ql AFTER attn
    float* attn = out;                            // d_out as attn scratch

    hipLaunchKernelGGL(splitX_kernel, dim3((M_ * 100 + 255) / 256), dim3(256), 0, stream,
                       X, Xh, Xl);
    hipLaunchKernelGGL(castWt_kernel, dim3(DP_ / 32, NKT, 3), dim3(256), 0, stream,
                       Wq, Wk, Wgc, Bqh, Bql, Bkh, Bkl, Bgh, Bgl);

    hipLaunchKernelGGL(gemm_qk_kernel, dim3(14, 128), dim3(256), 0, stream,
                       Xh, Xl, Bqh, Bql, Bkh, Bkl, bq, bk, Qh, Ql, Kh, Kl);

    hipLaunchKernelGGL(attn_mfma, dim3(512), dim3(256), 0, stream,
                       Qh, Ql, Kh, Kl, attn, diag, candv, candi);
    hipLaunchKernelGGL(merge_kernel, dim3(B_), dim3(64), 0, stream,
                       attn, candv, candi, tidx, tval);

    // Hd GEMM (2-term, Xh only) after attn: output aliases dead Qh/Ql region
    hipLaunchKernelGGL(gemm_hd_kernel, dim3(7, 128), dim3(256), 0, stream,
                       Xh, Bgh, Bgl, Hd);

    hipLaunchKernelGGL(out_kernel, dim3(M_), dim3(256), 0, stream,
                       Hd, diag, tidx, tval, bgc, out);
}

// Round 11
// 512.204 us; speedup vs baseline: 4.9477x; 1.1722x over previous
//
#include <hip/hip_runtime.h>

#define B_  32
#define N_  512
#define D_  791
#define H_  7
#define DK_ 113
#define M_  (B_*N_)
#define KP_ 800              // K-dim padded to mult of 32
#define DP_ 896              // per-head-padded col dim: 7 heads x 128
#define NKT 25               // KP_/32 K-tiles

typedef __attribute__((ext_vector_type(8))) short bf16x8;
typedef __attribute__((ext_vector_type(4))) float f32x4;

// ---------------- bf16 split helpers (RNE) ----------------
__device__ __forceinline__ ushort f2bf_rn(float x) {
    uint u = __float_as_uint(x);
    uint r = (u + 0x7FFFu + ((u >> 16) & 1u)) >> 16;
    return (ushort)r;
}
__device__ __forceinline__ float bf2f(ushort h) {
    return __uint_as_float(((uint)h) << 16);
}
__device__ __forceinline__ void split_bf16(float x, ushort& h, ushort& l) {
    h = f2bf_rn(x);
    l = f2bf_rn(x - bf2f(h));
}

// ---------------- async global->LDS 16B helper ----------------
__device__ __forceinline__ void gload16(const void* g, void* l) {
    __builtin_amdgcn_global_load_lds(
        (const __attribute__((address_space(1))) void*)g,
        (__attribute__((address_space(3))) void*)l, 16, 0, 0);
}

// ---------- X -> split bf16 Xh/Xl [16384][800] (zero-pad K) ----------
__global__ __launch_bounds__(256)
void splitX_kernel(const float* __restrict__ X, ushort* __restrict__ Xh,
                   ushort* __restrict__ Xl)
{
    int g = blockIdx.x * 256 + threadIdx.x;       // 0 .. M_*100-1
    if (g >= M_ * 100) return;
    int row = g / 100, grp = g % 100;
    int k0 = grp * 8;
    float v[8];
    if (k0 + 8 <= D_) {
        const float* p = X + (size_t)row * D_ + k0;
        #pragma unroll
        for (int i = 0; i < 8; ++i) v[i] = p[i];
    } else {
        #pragma unroll
        for (int i = 0; i < 8; ++i) {
            int k = k0 + i;
            v[i] = (k < D_) ? X[(size_t)row * D_ + k] : 0.f;
        }
    }
    bf16x8 hv, lv;
    #pragma unroll
    for (int i = 0; i < 8; ++i) {
        ushort h, l; split_bf16(v[i], h, l);
        hv[i] = (short)h; lv[i] = (short)l;
    }
    *(bf16x8*)&Xh[(size_t)row * KP_ + k0] = hv;
    *(bf16x8*)&Xl[(size_t)row * KP_ + k0] = lv;
}

// ---------- W -> transposed/padded/split Bt[pc][k], 32x32 LDS tiles ----------
__global__ __launch_bounds__(256)
void castWt_kernel(const float* __restrict__ W0, const float* __restrict__ W1,
                   const float* __restrict__ W2,
                   ushort* __restrict__ B0h, ushort* __restrict__ B0l,
                   ushort* __restrict__ B1h, ushort* __restrict__ B1l,
                   ushort* __restrict__ B2h, ushort* __restrict__ B2l)
{
    __shared__ ushort WsH[32][34], WsL[32][34];
    const int pc0 = blockIdx.x * 32;              // 0..895 step 32
    const int k0  = blockIdx.y * 32;              // 0..799 step 32
    const int w   = blockIdx.z;
    const float* W = (w == 0) ? W0 : (w == 1) ? W1 : W2;
    ushort* Bh = (w == 0) ? B0h : (w == 1) ? B1h : B2h;
    ushort* Bl = (w == 0) ? B0l : (w == 1) ? B1l : B2l;
    const int tx = threadIdx.x & 31, ty = threadIdx.x >> 5;   // 32 x 8

    #pragma unroll
    for (int r = 0; r < 4; ++r) {
        int kl = ty + 8 * r, k = k0 + kl;
        int pc = pc0 + tx;
        int src;
        if (w == 2) src = (pc < D_) ? pc : -1;
        else { int hh = pc >> 7, off = pc & 127; src = (off < DK_) ? hh * DK_ + off : -1; }
        float v = (src >= 0 && k < D_) ? W[(size_t)k * D_ + src] : 0.f;
        ushort h, l; split_bf16(v, h, l);
        WsH[tx][kl] = h; WsL[tx][kl] = l;
    }
    __syncthreads();
    #pragma unroll
    for (int r = 0; r < 4; ++r) {
        int pcl = ty + 8 * r, pc = pc0 + pcl;
        int k = k0 + tx;
        Bh[(size_t)pc * KP_ + k] = WsH[pcl][tx];
        Bl[(size_t)pc * KP_ + k] = WsL[pcl][tx];
    }
}

// ======== single-buffer GEMM staging (proven 202us/697TF structure) ========
// LDS tile [128 rows][32 k] ushort, linear; both-sides chunk swizzle
// q' = q ^ ((row>>1)&3) applied to the GLOBAL source and the LDS read.
#define STAGE_PAIR(dH, dL, srcH, srcL, rowBase, kk0)                         \
    {                                                                        \
        _Pragma("unroll")                                                    \
        for (int j = 0; j < 2; ++j) {                                        \
            int c  = t + 256 * j;                                            \
            int r  = c >> 2, q = c & 3;                                      \
            int qs = q ^ ((r >> 1) & 3);                                     \
            size_t go = (size_t)(rowBase + r) * KP_ + (kk0) + qs * 8;        \
            int lofs = ((t & 192) + 256 * j) * 8;                            \
            gload16(&srcH[go], (dH) + lofs);                                 \
            gload16(&srcL[go], (dL) + lofs);                                 \
        }                                                                    \
    }
#define STAGE_ONE(dH, srcH, rowBase, kk0)                                    \
    {                                                                        \
        _Pragma("unroll")                                                    \
        for (int j = 0; j < 2; ++j) {                                        \
            int c  = t + 256 * j;                                            \
            int r  = c >> 2, q = c & 3;                                      \
            int qs = q ^ ((r >> 1) & 3);                                     \
            size_t go = (size_t)(rowBase + r) * KP_ + (kk0) + qs * 8;        \
            int lofs = ((t & 192) + 256 * j) * 8;                            \
            gload16(&srcH[go], (dH) + lofs);                                 \
        }                                                                    \
    }

struct GemmAcc { f32x4 a[4][4]; };

// -------- fused Q+K GEMM: grid (14,128), XCD-chunked, single-buffer --------
__global__ __launch_bounds__(256)
void gemm_qk_kernel(const ushort* __restrict__ Xh, const ushort* __restrict__ Xl,
                    const ushort* __restrict__ Bqh, const ushort* __restrict__ Bql,
                    const ushort* __restrict__ Bkh, const ushort* __restrict__ Bkl,
                    const float* __restrict__ bq, const float* __restrict__ bk,
                    ushort* __restrict__ Qh, ushort* __restrict__ Ql,
                    ushort* __restrict__ Kh, ushort* __restrict__ Kl)
{
    __shared__ ushort AsH[128*32], AsL[128*32], BsH[128*32], BsL[128*32];
    const int flat = blockIdx.x + 14 * blockIdx.y;        // 0..1791
    const int nid  = (flat & 7) * 224 + (flat >> 3);      // XCD-chunked
    const int by = nid / 14, bx = nid % 14;
    const int w = bx / 7, ct = bx % 7;
    const int row0 = by * 128, col0 = ct * 128;
    const ushort* Bh = w ? Bkh : Bqh;
    const ushort* Bl = w ? Bkl : Bql;
    const float* bias = w ? bk : bq;
    ushort* Ch = w ? Kh : Qh;
    ushort* Cl = w ? Kl : Ql;

    const int t = threadIdx.x, lane = t & 63, wid = t >> 6;
    const int wr = wid >> 1, wc = wid & 1;
    const int fr = lane & 15, kq = lane >> 4;

    GemmAcc acc;
    #pragma unroll
    for (int m = 0; m < 4; ++m)
        #pragma unroll
        for (int n = 0; n < 4; ++n) acc.a[m][n] = (f32x4){0.f,0.f,0.f,0.f};

    for (int k0 = 0; k0 < KP_; k0 += 32) {
        STAGE_PAIR(AsH, AsL, Xh, Xl, row0, k0)
        STAGE_PAIR(BsH, BsL, Bh, Bl, col0, k0)
        __syncthreads();                    // drains vmcnt before LDS reads

        bf16x8 aH[4], aL[4], bH[4], bL[4];
        #pragma unroll
        for (int m = 0; m < 4; ++m) {
            int r = wr * 64 + m * 16 + fr;
            int off = r * 32 + (kq ^ ((r >> 1) & 3)) * 8;
            aH[m] = *(const bf16x8*)&AsH[off];
            aL[m] = *(const bf16x8*)&AsL[off];
        }
        #pragma unroll
        for (int n = 0; n < 4; ++n) {
            int c = wc * 64 + n * 16 + fr;
            int off = c * 32 + (kq ^ ((c >> 1) & 3)) * 8;
            bH[n] = *(const bf16x8*)&BsH[off];
            bL[n] = *(const bf16x8*)&BsL[off];
        }
        #pragma unroll
        for (int m = 0; m < 4; ++m)
            #pragma unroll
            for (int n = 0; n < 4; ++n) {
                acc.a[m][n] = __builtin_amdgcn_mfma_f32_16x16x32_bf16(aH[m], bH[n], acc.a[m][n], 0, 0, 0);
                acc.a[m][n] = __builtin_amdgcn_mfma_f32_16x16x32_bf16(aH[m], bL[n], acc.a[m][n], 0, 0, 0);
                acc.a[m][n] = __builtin_amdgcn_mfma_f32_16x16x32_bf16(aL[m], bH[n], acc.a[m][n], 0, 0, 0);
            }
        __syncthreads();                    // LDS safe for next stage
    }

    // epilogue: split-bf16 padded output [row][896]
    const int orow = kq * 4;
    #pragma unroll
    for (int n = 0; n < 4; ++n) {
        int pc = col0 + wc * 64 + n * 16 + fr;
        int hh = pc >> 7, off = pc & 127;
        float bb = (off < DK_) ? bias[hh * DK_ + off] : 0.f;
        #pragma unroll
        for (int m = 0; m < 4; ++m)
            #pragma unroll
            for (int j = 0; j < 4; ++j) {
                int gr = row0 + wr * 64 + m * 16 + orow + j;
                float v = acc.a[m][n][j] + bb;
                ushort h, l; split_bf16(v, h, l);
                Ch[(size_t)gr * DP_ + pc] = h;
                Cl[(size_t)gr * DP_ + pc] = l;
            }
    }
}

// -------- Hd GEMM (2-term Xh*(Wh+Wl)): grid (7,128), single-buffer --------
__global__ __launch_bounds__(256)
void gemm_hd_kernel(const ushort* __restrict__ Xh,
                    const ushort* __restrict__ Bgh, const ushort* __restrict__ Bgl,
                    float* __restrict__ Cf)
{
    __shared__ ushort AsH[128*32], BsH[128*32], BsL[128*32];
    const int flat = blockIdx.x + 7 * blockIdx.y;         // 0..895
    const int nid  = (flat & 7) * 112 + (flat >> 3);
    const int by = nid / 7, bx = nid % 7;
    const int row0 = by * 128, col0 = bx * 128;

    const int t = threadIdx.x, lane = t & 63, wid = t >> 6;
    const int wr = wid >> 1, wc = wid & 1;
    const int fr = lane & 15, kq = lane >> 4;

    GemmAcc acc;
    #pragma unroll
    for (int m = 0; m < 4; ++m)
        #pragma unroll
        for (int n = 0; n < 4; ++n) acc.a[m][n] = (f32x4){0.f,0.f,0.f,0.f};

    for (int k0 = 0; k0 < KP_; k0 += 32) {
        STAGE_ONE(AsH, Xh, row0, k0)
        STAGE_PAIR(BsH, BsL, Bgh, Bgl, col0, k0)
        __syncthreads();

        bf16x8 aH[4], bH[4], bL[4];
        #pragma unroll
        for (int m = 0; m < 4; ++m) {
            int r = wr * 64 + m * 16 + fr;
            int off = r * 32 + (kq ^ ((r >> 1) & 3)) * 8;
            aH[m] = *(const bf16x8*)&AsH[off];
        }
        #pragma unroll
        for (int n = 0; n < 4; ++n) {
            int c = wc * 64 + n * 16 + fr;
            int off = c * 32 + (kq ^ ((c >> 1) & 3)) * 8;
            bH[n] = *(const bf16x8*)&BsH[off];
            bL[n] = *(const bf16x8*)&BsL[off];
        }
        #pragma unroll
        for (int m = 0; m < 4; ++m)
            #pragma unroll
            for (int n = 0; n < 4; ++n) {
                acc.a[m][n] = __builtin_amdgcn_mfma_f32_16x16x32_bf16(aH[m], bH[n], acc.a[m][n], 0, 0, 0);
                acc.a[m][n] = __builtin_amdgcn_mfma_f32_16x16x32_bf16(aH[m], bL[n], acc.a[m][n], 0, 0, 0);
            }
        __syncthreads();
    }

    const int orow = kq * 4;
    #pragma unroll
    for (int n = 0; n < 4; ++n) {
        int gc = col0 + wc * 64 + n * 16 + fr;
        if (gc < D_) {
            #pragma unroll
            for (int m = 0; m < 4; ++m)
                #pragma unroll
                for (int j = 0; j < 4; ++j) {
                    int gr = row0 + wr * 64 + m * 16 + orow + j;
                    Cf[(size_t)gr * D_ + gc] = acc.a[m][n][j];
                }
        }
    }
}

// -------- MFMA attention + fused diag + per-block top-2 candidates --------
// K staged via global_load_lds: LINEAR LDS dest, pre-swizzled GLOBAL chunk
// cs = cl ^ (key&3); read side applies the same XOR (rule-#21 involution).
__global__ __launch_bounds__(256, 2)
void attn_mfma(const ushort* __restrict__ Qh, const ushort* __restrict__ Ql,
               const ushort* __restrict__ Kh, const ushort* __restrict__ Kl,
               float* __restrict__ attn, float* __restrict__ diag,
               float* __restrict__ candv, int* __restrict__ candi)
{
    __shared__ ushort KsH[512*32];   // 32 KB
    __shared__ ushort KsL[512*32];   // 32 KB
    __shared__ float redA[4][32];
    __shared__ float redB[4][32];
    __shared__ float wv[8]; __shared__ int wi[8];

    const int t = threadIdx.x, lane = t & 63, w = t >> 6;
    const int bid = blockIdx.x;
    const int swz = (bid & 7) * 64 + (bid >> 3);   // XCD-contiguous batches
    const int b = swz >> 4, r0 = (swz & 15) * 32;
    const int fr = lane & 15, kq = lane >> 4, kg = kq * 8;
    const float scale = 0.09407208683f;            // 1/sqrt(113)

    f32x4 accA[2][8];
    #pragma unroll
    for (int m = 0; m < 2; ++m)
        #pragma unroll
        for (int n = 0; n < 8; ++n) accA[m][n] = (f32x4){0.f,0.f,0.f,0.f};

    for (int h = 0; h < H_; ++h) {
        f32x4 S[2][8];
        #pragma unroll
        for (int m = 0; m < 2; ++m)
            #pragma unroll
            for (int n = 0; n < 8; ++n) S[m][n] = (f32x4){0.f,0.f,0.f,0.f};

        #pragma unroll
        for (int kk = 0; kk < 4; ++kk) {
            // async K stage: 64 KB via gload16, linear dest + swizzled source
            #pragma unroll
            for (int i = 0; i < 8; ++i) {
                int g = t + 256 * i;
                int key = g >> 2, cl = g & 3;
                int cs = cl ^ (key & 3);
                size_t go = (size_t)(b * N_ + key) * DP_ + h * 128 + kk * 32 + cs * 8;
                int lofs = ((t & 192) + 256 * i) * 8;
                gload16(&Kh[go], KsH + lofs);
                gload16(&Kl[go], KsL + lofs);
            }
            bf16x8 qH[2], qL[2];
            #pragma unroll
            for (int m = 0; m < 2; ++m) {
                size_t qo = (size_t)(b * N_ + r0 + m * 16 + fr) * DP_ + h * 128 + kk * 32 + kg;
                qH[m] = *(const bf16x8*)&Qh[qo];
                qL[m] = *(const bf16x8*)&Ql[qo];
            }
            __syncthreads();                 // drains gload vmcnt
            #pragma unroll
            for (int n = 0; n < 8; ++n) {
                int key = w * 128 + n * 16 + fr;
                int lo = key * 32 + ((kq ^ (key & 3)) * 8);
                bf16x8 bH = *(const bf16x8*)&KsH[lo];
                bf16x8 bL = *(const bf16x8*)&KsL[lo];
                #pragma unroll
                for (int m = 0; m < 2; ++m) {
                    S[m][n] = __builtin_amdgcn_mfma_f32_16x16x32_bf16(qH[m], bH, S[m][n], 0, 0, 0);
                    S[m][n] = __builtin_amdgcn_mfma_f32_16x16x32_bf16(qH[m], bL, S[m][n], 0, 0, 0);
                    S[m][n] = __builtin_amdgcn_mfma_f32_16x16x32_bf16(qL[m], bH, S[m][n], 0, 0, 0);
                }
            }
            __syncthreads();
        }

        // ---- softmax over keys for each of the 32 rows ----
        float fm[2][4];
        #pragma unroll
        for (int m = 0; m < 2; ++m)
            #pragma unroll
            for (int j = 0; j < 4; ++j) {
                float mx = -1e30f;
                #pragma unroll
                for (int n = 0; n < 8; ++n) {
                    S[m][n][j] *= scale;
                    mx = fmaxf(mx, S[m][n][j]);
                }
                #pragma unroll
                for (int d = 1; d < 16; d <<= 1) mx = fmaxf(mx, __shfl_xor(mx, d));
                fm[m][j] = mx;
            }
        if ((lane & 15) == 0) {
            #pragma unroll
            for (int m = 0; m < 2; ++m)
                #pragma unroll
                for (int j = 0; j < 4; ++j)
                    redA[w][m * 16 + kq * 4 + j] = fm[m][j];
        }
        __syncthreads();
        #pragma unroll
        for (int m = 0; m < 2; ++m)
            #pragma unroll
            for (int j = 0; j < 4; ++j) {
                int q = m * 16 + kq * 4 + j;
                float mx = redA[0][q];
                mx = fmaxf(mx, redA[1][q]);
                mx = fmaxf(mx, redA[2][q]);
                mx = fmaxf(mx, redA[3][q]);
                fm[m][j] = mx;
            }
        float sm[2][4];
        #pragma unroll
        for (int m = 0; m < 2; ++m)
            #pragma unroll
            for (int j = 0; j < 4; ++j) {
                float s = 0.f;
                #pragma unroll
                for (int n = 0; n < 8; ++n) {
                    float e = __expf(S[m][n][j] - fm[m][j]);
                    S[m][n][j] = e; s += e;
                }
                #pragma unroll
                for (int d = 1; d < 16; d <<= 1) s += __shfl_xor(s, d);
                sm[m][j] = s;
            }
        if ((lane & 15) == 0) {
            #pragma unroll
            for (int m = 0; m < 2; ++m)
                #pragma unroll
                for (int j = 0; j < 4; ++j)
                    redB[w][m * 16 + kq * 4 + j] = sm[m][j];
        }
        __syncthreads();
        #pragma unroll
        for (int m = 0; m < 2; ++m)
            #pragma unroll
            for (int j = 0; j < 4; ++j) {
                int q = m * 16 + kq * 4 + j;
                float s = redB[0][q] + redB[1][q] + redB[2][q] + redB[3][q];
                float rinv = 1.f / s;
                #pragma unroll
                for (int n = 0; n < 8; ++n)
                    accA[m][n][j] += S[m][n][j] * rinv;
            }
        __syncthreads();   // redA/redB safe for next head
    }

    // ---- write attn rows + fused diagonal extraction ----
    float* ab = attn + (size_t)b * N_ * N_;
    #pragma unroll
    for (int m = 0; m < 2; ++m)
        #pragma unroll
        for (int j = 0; j < 4; ++j) {
            int row = r0 + m * 16 + kq * 4 + j;
            float* ar = ab + (size_t)row * N_;
            #pragma unroll
            for (int n = 0; n < 8; ++n) {
                int col = w * 128 + n * 16 + fr;
                ar[col] = accA[m][n][j];
                if (col == row) diag[b * N_ + row] = accA[m][n][j];
            }
        }

    // ---- block-local top-2 over register values ----
    float v1 = -1e30f, v2 = -1e30f; int i1 = 0, i2 = 0;
    #pragma unroll
    for (int m = 0; m < 2; ++m)
        #pragma unroll
        for (int n = 0; n < 8; ++n)
            #pragma unroll
            for (int j = 0; j < 4; ++j) {
                float v = accA[m][n][j];
                int row = r0 + m * 16 + kq * 4 + j;
                int col = w * 128 + n * 16 + fr;
                int idx = row * N_ + col;
                if (v > v1)      { v2 = v1; i2 = i1; v1 = v; i1 = idx; }
                else if (v > v2) { v2 = v;  i2 = idx; }
            }
    #pragma unroll
    for (int d = 1; d < 64; d <<= 1) {
        float ov1 = __shfl_xor(v1, d); int oi1 = __shfl_xor(i1, d);
        float ov2 = __shfl_xor(v2, d); int oi2 = __shfl_xor(i2, d);
        if (ov1 > v1)      { v2 = v1; i2 = i1; v1 = ov1; i1 = oi1; }
        else if (ov1 > v2) { v2 = ov1; i2 = oi1; }
        if (ov2 > v1)      { v2 = v1; i2 = i1; v1 = ov2; i1 = oi2; }
        else if (ov2 > v2) { v2 = ov2; i2 = oi2; }
    }
    if (lane == 0) { wv[w*2] = v1; wi[w*2] = i1; wv[w*2+1] = v2; wi[w*2+1] = i2; }
    __syncthreads();
    if (t == 0) {
        float g1 = -1e30f, g2 = -1e30f; int gi1 = 0, gi2 = 0;
        for (int e = 0; e < 8; ++e) {
            float v = wv[e]; int ii = wi[e];
            if (v > g1)      { g2 = g1; gi2 = gi1; g1 = v; gi1 = ii; }
            else if (v > g2) { g2 = v; gi2 = ii; }
        }
        int cb = (b * 16 + (swz & 15)) * 2;
        candv[cb] = g1; candi[cb] = gi1;
        candv[cb+1] = g2; candi[cb+1] = gi2;
    }
}

// -------- merge per-batch candidates + gather transposes --------
__global__ __launch_bounds__(64)
void merge_kernel(const float* __restrict__ attn, const float* __restrict__ candv,
                  const int* __restrict__ candi,
                  int* __restrict__ tidx, float* __restrict__ tval)
{
    const int b = blockIdx.x;
    if (threadIdx.x != 0) return;
    const float* ab = attn + (size_t)b * N_ * N_;
    float v1 = -1e30f, v2 = -1e30f; int i1 = 0, i2 = 0;
    for (int s = 0; s < 32; ++s) {
        float v = candv[b * 32 + s]; int ii = candi[b * 32 + s];
        if (v > v1)      { v2 = v1; i2 = i1; v1 = v; i1 = ii; }
        else if (v > v2) { v2 = v; i2 = ii; }
    }
    int r1 = i1 / N_, c1 = i1 % N_;
    int r2 = i2 / N_, c2 = i2 % N_;
    tidx[b*4+0] = r1; tidx[b*4+1] = c1; tidx[b*4+2] = r2; tidx[b*4+3] = c2;
    tval[b*4+0] = ab[(size_t)r1 * N_ + c1];
    tval[b*4+1] = ab[(size_t)c1 * N_ + r1];
    tval[b*4+2] = ab[(size_t)r2 * N_ + c2];
    tval[b*4+3] = ab[(size_t)c2 * N_ + r2];
}

// -------- sparse graph-conv epilogue --------
__global__ __launch_bounds__(256)
void out_kernel(const float* __restrict__ Hd, const float* __restrict__ diag,
                const int* __restrict__ tidx, const float* __restrict__ tval,
                const float* __restrict__ bgc, float* __restrict__ out)
{
    const int bn = blockIdx.x;
    const int b = bn >> 9, n = bn & 511;
    const int t = threadIdx.x;

    const int r1 = tidx[b*4+0], c1 = tidx[b*4+1];
    const int r2 = tidx[b*4+2], c2 = tidx[b*4+3];

    int   mc[4]; float mv[4]; int nc = 0;
    if (r1 != c1) {
        if (n == r1) { mc[nc] = c1; mv[nc] = tval[b*4+0]; ++nc; }
        if (n == c1) { mc[nc] = r1; mv[nc] = tval[b*4+1]; ++nc; }
    }
    if (r2 != c2) {
        if (n == r2) { mc[nc] = c2; mv[nc] = tval[b*4+2]; ++nc; }
        if (n == c2) { mc[nc] = r2; mv[nc] = tval[b*4+3]; ++nc; }
    }
    const float dg = diag[bn];
    float denom = dg + 1.0f;
    for (int i = 0; i < nc; ++i) denom += mv[i];
    const float rd = 1.f / denom;

    const float* hn = Hd + (size_t)bn * D_;
    for (int d = t; d < D_; d += 256) {
        float acc = dg * hn[d];
        for (int i = 0; i < nc; ++i)
            acc += mv[i] * Hd[(size_t)(b * N_ + mc[i]) * D_ + d];
        float o = acc * rd + bgc[d];
        out[(size_t)bn * D_ + d] = fmaxf(o, 0.f);
    }
}

extern "C" void kernel_launch(void* const* d_in, const int* in_sizes, int n_in,
                              void* d_out, int out_size, void* d_ws, size_t ws_size,
                              hipStream_t stream)
{
    const float* X   = (const float*)d_in[0];
    const float* Wq  = (const float*)d_in[1];
    const float* bq  = (const float*)d_in[2];
    const float* Wk  = (const float*)d_in[3];
    const float* bk  = (const float*)d_in[4];
    const float* Wgc = (const float*)d_in[5];
    const float* bgc = (const float*)d_in[6];
    float* out = (float*)d_out;

    ushort* wsu = (ushort*)d_ws;
    const size_t MDP = (size_t)M_ * DP_;          // 14,680,064
    const size_t MKP = (size_t)M_ * KP_;          // 13,107,200
    ushort* Qh = wsu;
    ushort* Ql = wsu + MDP;
    ushort* Kh = wsu + 2 * MDP;
    ushort* Kl = wsu + 3 * MDP;
    ushort* Bt = wsu + 4 * MDP;
    const size_t BSZ = (size_t)DP_ * KP_;         // 716,800
    ushort* Bqh = Bt;            ushort* Bql = Bt + BSZ;
    ushort* Bkh = Bt + 2 * BSZ;  ushort* Bkl = Bt + 3 * BSZ;
    ushort* Bgh = Bt + 4 * BSZ;  ushort* Bgl = Bt + 5 * BSZ;
    ushort* Xh  = Bt + 6 * BSZ;                   // MKP ushorts (26.2 MB)
    float* diag  = (float*)(Xh + MKP);            // M_ floats
    int*   tidx  = (int*)(diag + M_);             // 128
    float* tval  = (float*)(tidx + 128);          // 128
    float* candv = tval + 128;                    // 1024
    int*   candi = (int*)(candv + 1024);          // 1024
    // Xl parked in d_out: consumed by gemm_qk only; attn overwrites it later.
    ushort* Xl  = (ushort*)d_out;
    float* Hd   = (float*)d_ws;                   // aliases Qh/Ql AFTER attn
    float* attn = out;                            // d_out as attn scratch

    hipLaunchKernelGGL(splitX_kernel, dim3((M_ * 100 + 255) / 256), dim3(256), 0, stream,
                       X, Xh, Xl);
    hipLaunchKernelGGL(castWt_kernel, dim3(DP_ / 32, NKT, 3), dim3(256), 0, stream,
                       Wq, Wk, Wgc, Bqh, Bql, Bkh, Bkl, Bgh, Bgl);

    hipLaunchKernelGGL(gemm_qk_kernel, dim3(14, 128), dim3(256), 0, stream,
                       Xh, Xl, Bqh, Bql, Bkh, Bkl, bq, bk, Qh, Ql, Kh, Kl);

    hipLaunchKernelGGL(attn_mfma, dim3(512), dim3(256), 0, stream,
                       Qh, Ql, Kh, Kl, attn, diag, candv, candi);
    hipLaunchKernelGGL(merge_kernel, dim3(B_), dim3(64), 0, stream,
                       attn, candv, candi, tidx, tval);

    // Hd GEMM (2-term, Xh only) after attn: output aliases dead Qh/Ql region
    hipLaunchKernelGGL(gemm_hd_kernel, dim3(7, 128), dim3(256), 0, stream,
                       Xh, Bgh, Bgl, Hd);

    hipLaunchKernelGGL(out_kernel, dim3(M_), dim3(256), 0, stream,
                       Hd, diag, tidx, tval, bgc, out);
}